// Round 8
// baseline (362.407 us; speedup 1.0000x reference)
//
#include <hip/hip_runtime.h>
#include <math.h>

#define CDIV(a,b) (((a)+(b)-1)/(b))
#define SEGCAP 768  // max edges per 32-node group in LDS fast path (mean 384)

typedef unsigned short ushort_t;

__device__ __forceinline__ ushort_t f2bf(float x) {
  unsigned u = __float_as_uint(x);
  unsigned r = (u + 0x7FFFu + ((u >> 16) & 1u)) >> 16;
  return (ushort_t)r;
}
__device__ __forceinline__ float bf2f(ushort_t s) {
  return __uint_as_float(((unsigned)s) << 16);
}

typedef __attribute__((ext_vector_type(8))) short bf16x8;
typedef __attribute__((ext_vector_type(4))) float f32x4;

// ---------------------------------------------------------------------------
// K1 (MFMA): feat = h @ fc_w.T via split-bf16 (hi+lo). el/er via an EXTRA
// 16-col MFMA tile: B_e[k][j] = wl[k][j] (j<8) / wr[k][j-8], where
// wl = fc_w.T·al blockdiag (computed per block in fp32, split to bf16 LDS).
// Wave wv computes the el/er tile for its own 16-row tile -- replaces the
// 256-shfl/lane butterfly epilogue.
// ---------------------------------------------------------------------------
__global__ __launch_bounds__(256) void k_gemm(const float* __restrict__ hm,
                                              const float* __restrict__ w,
                                              const float* __restrict__ al,
                                              const float* __restrict__ ar,
                                              ushort_t* __restrict__ featbf,
                                              float* __restrict__ el,
                                              float* __restrict__ er, int n) {
  __shared__ ushort_t Ahi[64 * 128];          // 16KB, XOR-swizzled rows
  __shared__ ushort_t Alo[64 * 128];          // 16KB
  __shared__ ushort_t BeL[4][4][16][16];      // 8KB: [kt][lg][lr][8 hi | 8 lo]
  const int t = threadIdx.x;
  const int wv = t >> 6;   // wave 0..3
  const int l = t & 63;    // lane
  const int lr = l & 15;   // row-in-tile (A) / col-in-tile (B,C)
  const int lg = l >> 4;   // k-group 0..3

  // ---- phase 0: wlr[k][j] fp32 in LDS (reuse Ahi region as float buffer) ----
  float* wlr = (float*)Ahi;  // [128][16]
  {
    int k = t >> 1, j0 = (t & 1) * 8;
    const float* av = (t & 1) ? ar : al;
    float out[8];
#pragma unroll
    for (int jh = 0; jh < 8; ++jh) out[jh] = 0.f;
#pragma unroll
    for (int jh = 0; jh < 8; ++jh) {
#pragma unroll
      for (int d = 0; d < 16; ++d) {
        out[jh] += w[(size_t)(jh * 16 + d) * 128 + k] * av[jh * 16 + d];
      }
    }
#pragma unroll
    for (int jh = 0; jh < 8; ++jh) wlr[k * 16 + j0 + jh] = out[jh];
  }
  __syncthreads();
  // ---- phase 1: one wave extracts+splits B_e into BeL ----
  if (t < 64) {
#pragma unroll
    for (int kt = 0; kt < 4; ++kt) {
      float xs[8];
#pragma unroll
      for (int i = 0; i < 8; ++i) xs[i] = wlr[(kt * 32 + lg * 8 + i) * 16 + lr];
#pragma unroll
      for (int i = 0; i < 8; ++i) {
        unsigned u = __float_as_uint(xs[i]);
        BeL[kt][lg][lr][i] = (ushort_t)(u >> 16);
        float resid = xs[i] - __uint_as_float(u & 0xFFFF0000u);
        BeL[kt][lg][lr][8 + i] = (ushort_t)(__float_as_uint(resid) >> 16);
      }
    }
  }

  // ---- B fragments (feat cols): fc_w split to bf16 hi/lo in registers ----
  bf16x8 Bhi[4][2], Blo[4][2];
#pragma unroll
  for (int ct = 0; ct < 2; ++ct) {
    const float* wr = w + (size_t)(32 * wv + ct * 16 + lr) * 128;
#pragma unroll
    for (int kt = 0; kt < 4; ++kt) {
      const float* wp = wr + kt * 32 + lg * 8;
      float4 v0 = *(const float4*)wp;
      float4 v1 = *(const float4*)(wp + 4);
      float xs[8] = {v0.x, v0.y, v0.z, v0.w, v1.x, v1.y, v1.z, v1.w};
      bf16x8 hi, lo;
#pragma unroll
      for (int i = 0; i < 8; ++i) {
        unsigned u = __float_as_uint(xs[i]);
        hi[i] = (short)(u >> 16);
        float resid = xs[i] - __uint_as_float(u & 0xFFFF0000u);
        lo[i] = (short)(__float_as_uint(resid) >> 16);
      }
      Bhi[kt][ct] = hi;
      Blo[kt][ct] = lo;
    }
  }
  __syncthreads();  // BeL ready; wlr region free for A staging

  const int base = blockIdx.x * 64;
#pragma unroll
  for (int r8 = 0; r8 < 8; ++r8) {
    int f = t + 256 * r8;
    int row = f >> 5, c4 = f & 31;
    int nidx = base + row;
    float4 v = make_float4(0.f, 0.f, 0.f, 0.f);
    if (nidx < n) v = ((const float4*)hm)[(size_t)nidx * 32 + c4];
    unsigned ux = __float_as_uint(v.x), uy = __float_as_uint(v.y);
    unsigned uz = __float_as_uint(v.z), uw = __float_as_uint(v.w);
    unsigned hi0 = (ux >> 16) | (uy & 0xFFFF0000u);
    unsigned hi1 = (uz >> 16) | (uw & 0xFFFF0000u);
    float rx = v.x - __uint_as_float(ux & 0xFFFF0000u);
    float ry = v.y - __uint_as_float(uy & 0xFFFF0000u);
    float rz = v.z - __uint_as_float(uz & 0xFFFF0000u);
    float rw = v.w - __uint_as_float(uw & 0xFFFF0000u);
    unsigned lo0 = (__float_as_uint(rx) >> 16) | (__float_as_uint(ry) & 0xFFFF0000u);
    unsigned lo1 = (__float_as_uint(rz) >> 16) | (__float_as_uint(rw) & 0xFFFF0000u);
    int uidx = row * 128 + ((c4 * 4) ^ ((row & 7) << 3));
    *(uint2*)&Ahi[uidx] = make_uint2(hi0, hi1);
    *(uint2*)&Alo[uidx] = make_uint2(lo0, lo1);
  }
  __syncthreads();

  f32x4 acc[4][2];
  f32x4 acce = (f32x4){0.f, 0.f, 0.f, 0.f};
#pragma unroll
  for (int mt = 0; mt < 4; ++mt)
#pragma unroll
    for (int ct = 0; ct < 2; ++ct) acc[mt][ct] = (f32x4){0.f, 0.f, 0.f, 0.f};

#pragma unroll
  for (int mt = 0; mt < 4; ++mt) {
    const int row = mt * 16 + lr;
    const int rbase = row * 128;
    const int swz = (row & 7) << 3;
#pragma unroll
    for (int kt = 0; kt < 4; ++kt) {
      const int k0 = (kt * 32 + lg * 8) ^ swz;
      bf16x8 ah = *(const bf16x8*)&Ahi[rbase + k0];
      bf16x8 ao = *(const bf16x8*)&Alo[rbase + k0];
#pragma unroll
      for (int ct = 0; ct < 2; ++ct) {
        acc[mt][ct] = __builtin_amdgcn_mfma_f32_16x16x32_bf16(ah, Bhi[kt][ct], acc[mt][ct], 0, 0, 0);
        acc[mt][ct] = __builtin_amdgcn_mfma_f32_16x16x32_bf16(ah, Blo[kt][ct], acc[mt][ct], 0, 0, 0);
        acc[mt][ct] = __builtin_amdgcn_mfma_f32_16x16x32_bf16(ao, Bhi[kt][ct], acc[mt][ct], 0, 0, 0);
      }
      if (mt == wv) {  // wave-uniform: this wave's el/er row-tile
        bf16x8 behi = *(const bf16x8*)&BeL[kt][lg][lr][0];
        bf16x8 belo = *(const bf16x8*)&BeL[kt][lg][lr][8];
        acce = __builtin_amdgcn_mfma_f32_16x16x32_bf16(ah, behi, acce, 0, 0, 0);
        acce = __builtin_amdgcn_mfma_f32_16x16x32_bf16(ah, belo, acce, 0, 0, 0);
        acce = __builtin_amdgcn_mfma_f32_16x16x32_bf16(ao, behi, acce, 0, 0, 0);
      }
    }
  }

  // ---- el/er epilogue: C layout col=lr (j), row=lg*4+rg ----
#pragma unroll
  for (int rg = 0; rg < 4; ++rg) {
    int node = base + wv * 16 + lg * 4 + rg;
    if (node < n) {
      if (lr < 8) el[(size_t)node * 8 + lr] = acce[rg];
      else        er[(size_t)node * 8 + (lr - 8)] = acce[rg];
    }
  }

  // ---- featbf: scatter acc -> LDS [row][col] bf16, then full-line stores ----
  __syncthreads();
#pragma unroll
  for (int mt = 0; mt < 4; ++mt)
#pragma unroll
    for (int ct = 0; ct < 2; ++ct) {
      const int colw = 32 * wv + ct * 16 + lr;
#pragma unroll
      for (int rg = 0; rg < 4; ++rg) {
        int row = mt * 16 + lg * 4 + rg;
        Ahi[row * 128 + colw] = f2bf(acc[mt][ct][rg]);
      }
    }
  __syncthreads();
#pragma unroll
  for (int r4 = 0; r4 < 4; ++r4) {
    int f = t + 256 * r4;
    int row = f >> 4, q = f & 15;
    int node = base + row;
    if (node < n)
      ((uint4*)featbf)[(size_t)node * 16 + q] = *(const uint4*)&Ahi[row * 128 + q * 8];
  }
}

// ---------------------------------------------------------------------------
// K-sort (fused hist + scan + scatter): 147 blocks <= 256 CUs -> all resident
// -> ticket/flag spin safe. All same-kernel cross-block handoffs are ATOMIC;
// threadfence release/acquire around the flag.
// meta layout (1200 uints), all ranges DISJOINT (r6/r7 bug: red-flag@395
// collided with histS[195]=meta[395] -> k_redfinal spin passed early ->
// garbage mu/scale):
//   histD@0..195  histS@200..395  redflag@396  sortflag@397
//   sortticket@398  redticket@399  curbD@400..595  curbS@600..795
//   bktoffD@800..996  bktoffS@1000..1196
// ---------------------------------------------------------------------------
__global__ __launch_bounds__(256) void k_sort(const int* __restrict__ src,
                                              const int* __restrict__ dst,
                                              unsigned* __restrict__ meta,
                                              unsigned* __restrict__ roffD,
                                              unsigned* __restrict__ roffS,
                                              uint2* __restrict__ recD,
                                              unsigned* __restrict__ recS,
                                              int nbkt, int n, int e, int nblk) {
  __shared__ unsigned lhD[256], lhS[256], lcD[256], lcS[256], s[256];
  __shared__ unsigned tk;
  int t = threadIdx.x;
  lhD[t] = 0; lhS[t] = 0;
  __syncthreads();
  int base = blockIdx.x * 4096;
  for (int k = 0; k < 16; ++k) {
    int i = base + t + 256 * k;
    if (i < e) {
      atomicAdd(&lhD[((unsigned)dst[i]) >> 8], 1u);
      atomicAdd(&lhS[((unsigned)src[i]) >> 8], 1u);
    }
  }
  __syncthreads();
  if (t < nbkt) {
    if (lhD[t]) atomicAdd(&meta[t], lhD[t]);
    if (lhS[t]) atomicAdd(&meta[200 + t], lhS[t]);
  }
  __threadfence();
  __syncthreads();
  if (t == 0) tk = atomicAdd(&meta[398], 1u);
  __syncthreads();
  if (tk == (unsigned)(nblk - 1)) {
    for (int g = 0; g < 2; ++g) {
      unsigned v = (t < nbkt) ? atomicAdd(&meta[g * 200 + t], 0u) : 0u;
      s[t] = v;
      __syncthreads();
      for (int off = 1; off < 256; off <<= 1) {
        unsigned x = (t >= off) ? s[t - off] : 0u;
        __syncthreads();
        s[t] += x;
        __syncthreads();
      }
      unsigned excl = s[t] - v;
      if (t < nbkt) {
        meta[800 + g * 200 + t] = excl;              // read by NEXT kernel (k_finB)
        atomicExch(&meta[400 + g * 200 + t], excl);  // read SAME-kernel: atomic
      }
      if (t == 0) meta[800 + g * 200 + nbkt] = (unsigned)e;
      __syncthreads();
    }
    if (t == 0) { roffD[n] = (unsigned)e; roffS[n] = (unsigned)e; }
    __threadfence();
    __syncthreads();
    if (t == 0) atomicExch(&meta[397], 1u);
  }
  if (t == 0) {
    while (atomicAdd(&meta[397], 0u) == 0u) __builtin_amdgcn_s_sleep(16);
  }
  __syncthreads();
  __threadfence();  // acquire
  if (t < nbkt) {
    lcD[t] = lhD[t] ? atomicAdd(&meta[400 + t], lhD[t]) : 0u;
    lcS[t] = lhS[t] ? atomicAdd(&meta[600 + t], lhS[t]) : 0u;
  }
  __syncthreads();
  for (int k = 0; k < 16; ++k) {
    int i = base + t + 256 * k;
    if (i < e) {
      unsigned d2 = (unsigned)dst[i], s2 = (unsigned)src[i];
      unsigned pD = atomicAdd(&lcD[d2 >> 8], 1u);
      recD[pD] = make_uint2(((d2 & 255u) << 16) | s2, (unsigned)i);
      unsigned pS = atomicAdd(&lcS[s2 >> 8], 1u);
      recS[pS] = ((s2 & 255u) << 24) | (unsigned)i;
    }
  }
}

// ---------------------------------------------------------------------------
// K-finB (combined dst+src fine placement, grid = 2*nbkt): b<nbkt -> dst path
// (+ fused edge-e leaky_relu -> bf16 aperm); else src path (eidS payload).
// Pure per-block work -- no cross-block sync.
// ---------------------------------------------------------------------------
__global__ __launch_bounds__(256) void k_finB(const uint2* __restrict__ recD,
                                              const unsigned* __restrict__ recS,
                                              const unsigned* __restrict__ meta,
                                              const float* __restrict__ el,
                                              const float* __restrict__ er,
                                              unsigned* __restrict__ roffD,
                                              unsigned* __restrict__ roffS,
                                              ushort_t* __restrict__ apermB,
                                              int* __restrict__ srcD,
                                              unsigned* __restrict__ eidD,
                                              unsigned* __restrict__ eidS,
                                              int nbkt, int n) {
  __shared__ float erL[256 * 8];
  __shared__ unsigned cnt1[256], cnt2[256], sc[256];
  int t = threadIdx.x;
  int b = blockIdx.x;
  if (b < nbkt) {
    const unsigned* bktoff = meta + 800;
    unsigned b0 = bktoff[b], b1 = bktoff[b + 1];
    int nb0 = b << 8;
    for (int k = 0; k < 8; ++k) {
      int idx = t + 256 * k;
      int node = nb0 + (idx >> 3);
      erL[idx] = (node < n) ? er[(size_t)nb0 * 8 + idx] : 0.f;
    }
    cnt1[t] = 0;
    __syncthreads();
    for (unsigned j = b0 + t; j < b1; j += 256) {
      unsigned nodeLoc = (recD[j].x >> 16) & 255u;
      atomicAdd(&cnt1[nodeLoc], 1u);
    }
    __syncthreads();
    unsigned v = cnt1[t];
    sc[t] = v;
    __syncthreads();
    for (int off = 1; off < 256; off <<= 1) {
      unsigned x = (t >= off) ? sc[t - off] : 0u;
      __syncthreads();
      sc[t] += x;
      __syncthreads();
    }
    unsigned excl = sc[t] - v;
    int node = nb0 + t;
    if (node < n) roffD[node] = b0 + excl;
    cnt2[t] = b0 + excl;
    __syncthreads();
    for (unsigned j = b0 + t; j < b1; j += 256) {
      uint2 r = recD[j];
      unsigned nodeLoc = (r.x >> 16) & 255u;
      unsigned srcv = r.x & 0xFFFFu;
      unsigned pos = atomicAdd(&cnt2[nodeLoc], 1u);
      float4 a0 = *(const float4*)&el[(size_t)srcv * 8];
      float4 a1 = *(const float4*)&el[(size_t)srcv * 8 + 4];
      const float* eb = &erL[nodeLoc * 8];
      float ev[8] = {a0.x + eb[0], a0.y + eb[1], a0.z + eb[2], a0.w + eb[3],
                     a1.x + eb[4], a1.y + eb[5], a1.z + eb[6], a1.w + eb[7]};
#pragma unroll
      for (int h2 = 0; h2 < 8; ++h2) ev[h2] = ev[h2] > 0.f ? ev[h2] : 0.2f * ev[h2];
      unsigned q0 = (unsigned)f2bf(ev[0]) | ((unsigned)f2bf(ev[1]) << 16);
      unsigned q1 = (unsigned)f2bf(ev[2]) | ((unsigned)f2bf(ev[3]) << 16);
      unsigned q2 = (unsigned)f2bf(ev[4]) | ((unsigned)f2bf(ev[5]) << 16);
      unsigned q3 = (unsigned)f2bf(ev[6]) | ((unsigned)f2bf(ev[7]) << 16);
      *(uint4*)&apermB[(size_t)pos * 8] = make_uint4(q0, q1, q2, q3);
      srcD[pos] = (int)srcv;
      eidD[pos] = r.y;
    }
  } else {
    int bs = b - nbkt;
    const unsigned* bktoff = meta + 1000;
    unsigned b0 = bktoff[bs], b1 = bktoff[bs + 1];
    int nb0 = bs << 8;
    cnt1[t] = 0;
    __syncthreads();
    for (unsigned j = b0 + t; j < b1; j += 256) {
      unsigned nodeLoc = recS[j] >> 24;
      atomicAdd(&cnt1[nodeLoc], 1u);
    }
    __syncthreads();
    unsigned v = cnt1[t];
    sc[t] = v;
    __syncthreads();
    for (int off = 1; off < 256; off <<= 1) {
      unsigned x = (t >= off) ? sc[t - off] : 0u;
      __syncthreads();
      sc[t] += x;
      __syncthreads();
    }
    unsigned excl = sc[t] - v;
    int node = nb0 + t;
    if (node < n) roffS[node] = b0 + excl;
    cnt2[t] = b0 + excl;
    __syncthreads();
    for (unsigned j = b0 + t; j < b1; j += 256) {
      unsigned r = recS[j];
      unsigned nodeLoc = r >> 24;
      unsigned pos = atomicAdd(&cnt2[nodeLoc], 1u);
      eidS[pos] = r & 0x00FFFFFFu;
    }
  }
}

// ---------------------------------------------------------------------------
// K-attn (fused): softmax -> dst-half R-accumulation (linearity: sum_w =
// deg*(1-B2) - W2·R) -> per-edge writeback. Serial per-(node,h) loops are
// pure LDS+VALU; normalize pass folded into MLP pass via inv-prescaled W1.
// ---------------------------------------------------------------------------
__global__ __launch_bounds__(256) void k_attn(const unsigned* __restrict__ roffD,
                                              const unsigned* __restrict__ eidD,
                                              ushort_t* __restrict__ apermB,
                                              const float* __restrict__ aw1,
                                              const float* __restrict__ ab1,
                                              const float* __restrict__ aw2,
                                              const float* __restrict__ ab2,
                                              float* __restrict__ attn,
                                              float* __restrict__ swD, int n) {
  __shared__ float aL[SEGCAP * 8];
  __shared__ float W1[64], W2[64], B1[8], B2[8];
  __shared__ unsigned nb_[33];
  int t = threadIdx.x;
  if (t < 64) { W1[t] = aw1[t]; W2[t] = aw2[t]; }
  else if (t < 72) { B1[t - 64] = ab1[t - 64]; B2[t - 64] = ab2[t - 64]; }
  int g0 = blockIdx.x * 32;
  if (t < 33) {
    int node = g0 + t;
    nb_[t] = roffD[node < n ? node : n];
  }
  __syncthreads();
  unsigned b0 = nb_[0], b1 = nb_[32];
  unsigned count = b1 - b0;
  int ln = t >> 3, h = t & 7;
  int node = g0 + ln;
  const int l = t & 63, gbl = l & 56;
  if (count <= SEGCAP) {
    const unsigned* ap32 = (const unsigned*)apermB + (size_t)b0 * 4;
    for (unsigned k = t; k < count * 4; k += 256) {
      unsigned pk = ap32[k];
      aL[k * 2] = bf2f((ushort_t)(pk & 0xFFFFu));
      aL[k * 2 + 1] = bf2f((ushort_t)(pk >> 16));
    }
    __syncthreads();
    unsigned s0 = nb_[ln] - b0, s1 = nb_[ln + 1] - b0;
    float inv = 0.f;
    if (node < n) {
      float ssum = 0.f;
      for (unsigned j = s0; j < s1; ++j) {
        float ex = expf(aL[j * 8 + h]);
        aL[j * 8 + h] = ex;
        ssum += ex;
      }
      inv = ssum > 0.f ? 1.f / ssum : 0.f;
    }
    __syncthreads();
    float w1m[8];
#pragma unroll
    for (int m = 0; m < 8; ++m) w1m[m] = W1[h * 8 + m] * __shfl(inv, gbl | m);
    if (node < n) {
      float R = 0.f;
      for (unsigned j = s0; j < s1; ++j) {
        const float* a = &aL[j * 8];
        float acc = B1[h];
#pragma unroll
        for (int m = 0; m < 8; ++m) acc += a[m] * w1m[m];
        acc = acc > 0.f ? acc : 0.f;
        R += acc;
        aL[j * 8 + h] = a[h] * inv;  // normalize own slot (folded pass)
      }
      float sv = (float)(s1 - s0) * (1.f - B2[h]);
#pragma unroll
      for (int r = 0; r < 8; ++r) {
        int jj = (h + r) & 7;
        float Rj = __shfl(R, gbl | jj);
        sv -= W2[h * 8 + jj] * Rj;
      }
      swD[(size_t)node * 8 + h] = sv;
    }
    __syncthreads();
    for (unsigned eL = t; eL < count; eL += 256) {
      const float* a = &aL[eL * 8];
      unsigned ee = eidD[b0 + eL];
      float4* op = (float4*)&attn[(size_t)ee * 8];
      op[0] = make_float4(a[0], a[1], a[2], a[3]);
      op[1] = make_float4(a[4], a[5], a[6], a[7]);
      unsigned q0 = (unsigned)f2bf(a[0]) | ((unsigned)f2bf(a[1]) << 16);
      unsigned q1 = (unsigned)f2bf(a[2]) | ((unsigned)f2bf(a[3]) << 16);
      unsigned q2 = (unsigned)f2bf(a[4]) | ((unsigned)f2bf(a[5]) << 16);
      unsigned q3 = (unsigned)f2bf(a[6]) | ((unsigned)f2bf(a[7]) << 16);
      *(uint4*)&apermB[(size_t)(b0 + eL) * 8] = make_uint4(q0, q1, q2, q3);
    }
  } else {
    unsigned sb = nb_[ln], se = nb_[ln + 1];
    if (node < n) {
      float s = 0.f;
      for (unsigned j = sb; j < se; ++j) s += expf(bf2f(apermB[(size_t)j * 8 + h]));
      float inv = s > 0.f ? 1.f / s : 0.f;
      for (unsigned j = sb; j < se; ++j) {
        size_t p = (size_t)j * 8 + h;
        apermB[p] = f2bf(expf(bf2f(apermB[p])) * inv);
      }
    }
    __syncthreads();
    if (node < n) {
      float R = 0.f;
      for (unsigned j = sb; j < se; ++j) {
        float a[8];
#pragma unroll
        for (int m = 0; m < 8; ++m) a[m] = bf2f(apermB[(size_t)j * 8 + m]);
        float acc = B1[h];
#pragma unroll
        for (int m = 0; m < 8; ++m) acc += a[m] * W1[h * 8 + m];
        acc = acc > 0.f ? acc : 0.f;
        R += acc;
      }
      float sv = (float)(se - sb) * (1.f - B2[h]);
#pragma unroll
      for (int r = 0; r < 8; ++r) {
        int jj = (h + r) & 7;
        float Rj = __shfl(R, gbl | jj);
        sv -= W2[h * 8 + jj] * Rj;
      }
      swD[(size_t)node * 8 + h] = sv;
    }
    for (unsigned eL = t; eL < count; eL += 256) {
      unsigned j = b0 + eL;
      float a[8];
#pragma unroll
      for (int m = 0; m < 8; ++m) a[m] = bf2f(apermB[(size_t)j * 8 + m]);
      unsigned ee = eidD[j];
      float4* op = (float4*)&attn[(size_t)ee * 8];
      op[0] = make_float4(a[0], a[1], a[2], a[3]);
      op[1] = make_float4(a[4], a[5], a[6], a[7]);
    }
  }
}

// K5: src-half sum_w via fp32 attn-row gather (eidS coalesced; same-row lanes
// wave-merged; 4-wide unrolled gathers). Lane h computes only hidden unit h.
__global__ __launch_bounds__(256) void k_sumw_tr(const unsigned* __restrict__ roffS,
                                                 const unsigned* __restrict__ eidS,
                                                 const float* __restrict__ attn,
                                                 const float* __restrict__ swD,
                                                 const float* __restrict__ aw1,
                                                 const float* __restrict__ ab1,
                                                 const float* __restrict__ aw2,
                                                 const float* __restrict__ ab2,
                                                 const float* __restrict__ tw1,
                                                 const float* __restrict__ tb1,
                                                 float* __restrict__ tr, int n) {
  __shared__ float sw[32][9];
  __shared__ float W1[64], W2[64], T1[64], B1[8], B2[8], TB[8];
  int t = threadIdx.x;
  if (t < 64) { W1[t] = aw1[t]; W2[t] = aw2[t]; T1[t] = tw1[t]; }
  else if (t < 72) { B1[t - 64] = ab1[t - 64]; B2[t - 64] = ab2[t - 64]; TB[t - 64] = tb1[t - 64]; }
  __syncthreads();
  int ln = t >> 3, h = t & 7;
  int node = blockIdx.x * 32 + ln;
  const int gbl = (t & 63) & 56;
  float w1r[8];
#pragma unroll
  for (int m = 0; m < 8; ++m) w1r[m] = W1[h * 8 + m];
  const float B1h = B1[h];
  if (node < n) {
    unsigned b = roffS[node], en = roffS[node + 1];
    float R = 0.f;
    unsigned j = b;
    for (; j + 4 <= en; j += 4) {
      unsigned e0 = eidS[j], e1 = eidS[j + 1], e2 = eidS[j + 2], e3 = eidS[j + 3];
      const float* p0 = &attn[(size_t)e0 * 8];
      const float* p1 = &attn[(size_t)e1 * 8];
      const float* p2 = &attn[(size_t)e2 * 8];
      const float* p3 = &attn[(size_t)e3 * 8];
      float4 x00 = *(const float4*)p0, x01 = *(const float4*)(p0 + 4);
      float4 x10 = *(const float4*)p1, x11 = *(const float4*)(p1 + 4);
      float4 x20 = *(const float4*)p2, x21 = *(const float4*)(p2 + 4);
      float4 x30 = *(const float4*)p3, x31 = *(const float4*)(p3 + 4);
      float a0 = B1h + x00.x * w1r[0] + x00.y * w1r[1] + x00.z * w1r[2] + x00.w * w1r[3]
                     + x01.x * w1r[4] + x01.y * w1r[5] + x01.z * w1r[6] + x01.w * w1r[7];
      float a1 = B1h + x10.x * w1r[0] + x10.y * w1r[1] + x10.z * w1r[2] + x10.w * w1r[3]
                     + x11.x * w1r[4] + x11.y * w1r[5] + x11.z * w1r[6] + x11.w * w1r[7];
      float a2 = B1h + x20.x * w1r[0] + x20.y * w1r[1] + x20.z * w1r[2] + x20.w * w1r[3]
                     + x21.x * w1r[4] + x21.y * w1r[5] + x21.z * w1r[6] + x21.w * w1r[7];
      float a3 = B1h + x30.x * w1r[0] + x30.y * w1r[1] + x30.z * w1r[2] + x30.w * w1r[3]
                     + x31.x * w1r[4] + x31.y * w1r[5] + x31.z * w1r[6] + x31.w * w1r[7];
      R += (a0 > 0.f ? a0 : 0.f) + (a1 > 0.f ? a1 : 0.f) +
           (a2 > 0.f ? a2 : 0.f) + (a3 > 0.f ? a3 : 0.f);
    }
    for (; j < en; ++j) {
      unsigned e0 = eidS[j];
      const float* p0 = &attn[(size_t)e0 * 8];
      float4 x00 = *(const float4*)p0, x01 = *(const float4*)(p0 + 4);
      float a0 = B1h + x00.x * w1r[0] + x00.y * w1r[1] + x00.z * w1r[2] + x00.w * w1r[3]
                     + x01.x * w1r[4] + x01.y * w1r[5] + x01.z * w1r[6] + x01.w * w1r[7];
      R += a0 > 0.f ? a0 : 0.f;
    }
    float sv = swD[(size_t)node * 8 + h] + (float)(en - b) * (1.f - B2[h]);
#pragma unroll
    for (int r = 0; r < 8; ++r) {
      int jj = (h + r) & 7;
      float Rj = __shfl(R, gbl | jj);
      sv -= W2[h * 8 + jj] * Rj;
    }
    sw[ln][h] = sv;
  }
  __syncthreads();
  if (node < n) {
    float acc = TB[h];
#pragma unroll
    for (int m = 0; m < 8; ++m) acc += sw[ln][m] * T1[h * 8 + m];
    tr[(size_t)node * 8 + h] = acc > 0.f ? acc : 0.f;
  }
}

// K-msg (fused e_emb + BN stats): r1 form (measured 43.2us @ occ 54% --
// deeper pipelines r2/r3 both regressed; gather stream is occupancy/TLP-fed).
__global__ __launch_bounds__(256) void k_msg(const int* __restrict__ srcD,
                                             const unsigned* __restrict__ roff,
                                             const ushort_t* __restrict__ apermB,
                                             const ushort_t* __restrict__ featbf,
                                             const float* __restrict__ tr,
                                             const float* __restrict__ tw2,
                                             const float* __restrict__ tb2,
                                             const float* __restrict__ gat_bias,
                                             float* __restrict__ hout,
                                             float* __restrict__ partial, int n) {
  __shared__ float bn1[4][128], bn2[4][128];
  int t = threadIdx.x;
  int w = t >> 6, lane = t & 63;
  int col = lane * 2;
  int hh = lane >> 3;
  float w2a[8], w2b[8];
#pragma unroll
  for (int j = 0; j < 8; ++j) { w2a[j] = tw2[col * 8 + j]; w2b[j] = tw2[(col + 1) * 8 + j]; }
  float biasA = tb2[col] + gat_bias[col];
  float biasB = tb2[col + 1] + gat_bias[col + 1];
  float s1a = 0.f, s1b = 0.f, s2a = 0.f, s2b = 0.f;
  int nodeBase = blockIdx.x * 16 + w * 4;
  for (int ni = 0; ni < 4; ++ni) {
    int node = nodeBase + ni;
    if (node >= n) break;
    unsigned b = roff[node], en = roff[node + 1];
    float x0 = 0.f, x1 = 0.f;
    unsigned j = b;
    for (; j + 4 <= en; j += 4) {
      int sa = srcD[j], sb = srcD[j + 1], sc2 = srcD[j + 2], sd = srcD[j + 3];
      float av0 = bf2f(apermB[(size_t)j * 8 + hh]);
      float av1 = bf2f(apermB[(size_t)(j + 1) * 8 + hh]);
      float av2 = bf2f(apermB[(size_t)(j + 2) * 8 + hh]);
      float av3 = bf2f(apermB[(size_t)(j + 3) * 8 + hh]);
      unsigned p0 = *(const unsigned*)&featbf[(size_t)sa * 128 + col];
      unsigned p1 = *(const unsigned*)&featbf[(size_t)sb * 128 + col];
      unsigned p2 = *(const unsigned*)&featbf[(size_t)sc2 * 128 + col];
      unsigned p3 = *(const unsigned*)&featbf[(size_t)sd * 128 + col];
      x0 += bf2f((ushort_t)(p0 & 0xFFFFu)) * av0 + bf2f((ushort_t)(p1 & 0xFFFFu)) * av1 +
            bf2f((ushort_t)(p2 & 0xFFFFu)) * av2 + bf2f((ushort_t)(p3 & 0xFFFFu)) * av3;
      x1 += bf2f((ushort_t)(p0 >> 16)) * av0 + bf2f((ushort_t)(p1 >> 16)) * av1 +
            bf2f((ushort_t)(p2 >> 16)) * av2 + bf2f((ushort_t)(p3 >> 16)) * av3;
    }
    for (; j < en; ++j) {
      int sa = srcD[j];
      float av0 = bf2f(apermB[(size_t)j * 8 + hh]);
      unsigned p0 = *(const unsigned*)&featbf[(size_t)sa * 128 + col];
      x0 += bf2f((ushort_t)(p0 & 0xFFFFu)) * av0;
      x1 += bf2f((ushort_t)(p0 >> 16)) * av0;
    }
    const float* trn = &tr[(size_t)node * 8];
    float emA = biasA, emB = biasB;
#pragma unroll
    for (int jj = 0; jj < 8; ++jj) {
      float tv = trn[jj];
      emA += tv * w2a[jj];
      emB += tv * w2b[jj];
    }
    float v0 = x0 + emA, v1 = x1 + emB;
    *(float2*)&hout[(size_t)node * 128 + col] = make_float2(v0, v1);
    s1a += v0; s1b += v1; s2a += v0 * v0; s2b += v1 * v1;
  }
  bn1[w][col] = s1a; bn1[w][col + 1] = s1b;
  bn2[w][col] = s2a; bn2[w][col + 1] = s2b;
  __syncthreads();
  int f = t & 127;
  float acc;
  if (t < 128) acc = bn1[0][f] + bn1[1][f] + bn1[2][f] + bn1[3][f];
  else         acc = bn2[0][f] + bn2[1][f] + bn2[2][f] + bn2[3][f];
  partial[(size_t)blockIdx.x * 256 + t] = acc;
}

// ---------------------------------------------------------------------------
// K-redfinal (fused red + bnfin + final): 241 blocks <= 256 CUs -> resident.
// All cross-block handoffs atomic: bnacc atomicAdd, mu/scale atomicExch,
// flag atomicExch, reads atomicAdd(,0); threadfence release/acquire.
// Flag lives at meta[396] (396 is NOT in any hist/curb/bktoff range).
// ---------------------------------------------------------------------------
__global__ __launch_bounds__(256) void k_redfinal(const float* __restrict__ partial,
                                                  float* __restrict__ bnacc,
                                                  const float* __restrict__ gamma,
                                                  const float* __restrict__ beta,
                                                  const float* __restrict__ hin,
                                                  float* __restrict__ hout,
                                                  float* __restrict__ mu,
                                                  float* __restrict__ scale,
                                                  unsigned* __restrict__ ticket,
                                                  unsigned* __restrict__ flag,
                                                  int rows, int n, int nblk) {
  __shared__ float muL[128], scL[128], beL[128];
  __shared__ unsigned tk;
  int t = threadIdx.x;
  int r0 = blockIdx.x * 13, r1 = r0 + 13;
  if (r1 > rows) r1 = rows;
  float acc = 0.f;
  for (int r = r0; r < r1; ++r) acc += partial[(size_t)r * 256 + t];
  if (r0 < r1) atomicAdd(&bnacc[t], acc);
  __threadfence();
  __syncthreads();
  if (t == 0) tk = atomicAdd(ticket, 1u);
  __syncthreads();
  if (tk == (unsigned)(nblk - 1)) {
    if (t < 128) {
      float sm = atomicAdd(&bnacc[t], 0.f);          // coherent reads
      float sq = atomicAdd(&bnacc[128 + t], 0.f);
      float m = sm / (float)n;
      float v = sq / (float)n - m * m;
      atomicExch(&mu[t], m);                          // coherent writes
      atomicExch(&scale[t], rsqrtf(v + 1e-5f) * gamma[t]);
    }
    __threadfence();
    __syncthreads();
    if (t == 0) atomicExch(flag, 1u);
  }
  if (t == 0) {
    while (atomicAdd(flag, 0u) == 0u) __builtin_amdgcn_s_sleep(16);
  }
  __syncthreads();
  __threadfence();  // acquire
  if (t < 128) {
    muL[t] = atomicAdd(&mu[t], 0.f);
    scL[t] = atomicAdd(&scale[t], 0.f);
    beL[t] = beta[t];
  }
  __syncthreads();
  int total4 = n * 32;
  for (int i = blockIdx.x * 256 + t; i < total4; i += nblk * 256) {
    int c = (i & 31) * 4;
    float4 x = ((const float4*)hout)[i];
    float4 hi = ((const float4*)hin)[i];
    float y0 = (x.x - muL[c])     * scL[c]     + beL[c];
    float y1 = (x.y - muL[c + 1]) * scL[c + 1] + beL[c + 1];
    float y2 = (x.z - muL[c + 2]) * scL[c + 2] + beL[c + 2];
    float y3 = (x.w - muL[c + 3]) * scL[c + 3] + beL[c + 3];
    y0 = y0 > 0.f ? y0 : expm1f(y0);
    y1 = y1 > 0.f ? y1 : expm1f(y1);
    y2 = y2 > 0.f ? y2 : expm1f(y2);
    y3 = y3 > 0.f ? y3 : expm1f(y3);
    float4 o = make_float4(hi.x + y0, hi.y + y1, hi.z + y2, hi.w + y3);
    ((float4*)hout)[i] = o;
  }
}

extern "C" void kernel_launch(void* const* d_in, const int* in_sizes, int n_in,
                              void* d_out, int out_size, void* d_ws, size_t ws_size,
                              hipStream_t stream) {
  const float* h_in     = (const float*)d_in[0];
  const int*   esrc     = (const int*)d_in[1];
  const int*   edst     = (const int*)d_in[2];
  const float* fc_w     = (const float*)d_in[4];
  const float* attn_l   = (const float*)d_in[5];
  const float* attn_r   = (const float*)d_in[6];
  const float* gat_bias = (const float*)d_in[7];
  const float* aw1      = (const float*)d_in[8];
  const float* ab1      = (const float*)d_in[9];
  const float* aw2      = (const float*)d_in[10];
  const float* ab2      = (const float*)d_in[11];
  const float* tw1      = (const float*)d_in[12];
  const float* tb1      = (const float*)d_in[13];
  const float* tw2      = (const float*)d_in[14];
  const float* tb2      = (const float*)d_in[15];
  const float* gamma    = (const float*)d_in[16];
  const float* beta     = (const float*)d_in[17];

  const int n = in_sizes[0] / 128;  // 50000
  const int e = in_sizes[1];        // 600000
  const int nbkt = CDIV(n, 256);    // 196
  const int gridMsg = CDIV(n, 16);  // 3125
  const int nblkE = CDIV(e, 4096);  // 147  (<= 256 CUs: k_sort spin safe)
  const int nblkR = CDIV(gridMsg, 13);  // 241  (<= 256 CUs: k_redfinal spin safe)

  float* ws = (float*)d_ws;
  size_t OFF_FEAT  = 0;                          // n*128 ushorts = n*64 floats
  size_t OFF_EL    = OFF_FEAT + (size_t)n * 64;
  size_t OFF_ER    = OFF_EL + (size_t)n * 8;
  size_t OFF_ROFD  = OFF_ER + (size_t)n * 8;
  size_t OFF_ROFS  = OFF_ROFD + (size_t)(n + 16);
  size_t OFF_EIDD  = OFF_ROFS + (size_t)(n + 16);
  size_t OFF_SRCD  = OFF_EIDD + (size_t)e;
  size_t OFF_EIDS  = OFF_SRCD + (size_t)e;
  size_t OFF_APERM = OFF_EIDS + (size_t)e;       // bf16: e*8 ushorts = e*4 floats
  size_t OFF_PART  = OFF_APERM + (size_t)e * 4;
  size_t OFF_META  = OFF_PART + (size_t)gridMsg * 256;
  size_t OFF_BN    = OFF_META + 1200;

  ushort_t* featbf = (ushort_t*)(ws + OFF_FEAT);
  float*    el     = ws + OFF_EL;
  float*    er     = ws + OFF_ER;
  unsigned* roffD  = (unsigned*)(ws + OFF_ROFD);
  unsigned* roffS  = (unsigned*)(ws + OFF_ROFS);
  unsigned* eidD   = (unsigned*)(ws + OFF_EIDD);
  int*      srcD   = (int*)(ws + OFF_SRCD);
  unsigned* eidS   = (unsigned*)(ws + OFF_EIDS);
  ushort_t* apermB = (ushort_t*)(ws + OFF_APERM);
  float*    partial= ws + OFF_PART;
  unsigned* meta   = (unsigned*)(ws + OFF_META);
  float*    bnsum  = ws + OFF_BN;   // bnacc[256] = bnsum[128] ++ bnsq[128]
  float*    mu     = bnsum + 256;
  float*    scale  = bnsum + 384;
  float*    tr     = el;  // alias: el dead after k_finB (dst half)
  float*    swD    = er;  // alias: er dead after k_finB (dst half)

  float* hout = (float*)d_out;
  float* attn = (float*)d_out + (size_t)n * 128;
  uint2*    recD = (uint2*)attn;                          // dead once k_attn writes attn
  unsigned* recS = (unsigned*)(attn + (size_t)e * 2);

  hipMemsetAsync(meta, 0, 800 * sizeof(unsigned), stream);   // hists+flags+curb
  hipMemsetAsync(bnsum, 0, 256 * sizeof(float), stream);
  size_t head = (size_t)n * 128 + (size_t)e * 8;
  if ((size_t)out_size > head)
    hipMemsetAsync((float*)d_out + head, 0, ((size_t)out_size - head) * sizeof(float), stream);

  k_gemm<<<CDIV(n, 64), 256, 0, stream>>>(h_in, fc_w, attn_l, attn_r, featbf, el, er, n);

  // bucket sort (both graphs): single fused hist+scan+scatter launch
  k_sort<<<nblkE, 256, 0, stream>>>(esrc, edst, meta, roffD, roffS, recD, recS,
                                    nbkt, n, e, nblkE);
  // fine placement, dst+src combined
  k_finB<<<2 * nbkt, 256, 0, stream>>>(recD, recS, meta, el, er, roffD, roffS,
                                       apermB, srcD, eidD, eidS, nbkt, n);

  // fused softmax + dst-half R (pure LDS serial loops) + writebacks
  k_attn<<<CDIV(n, 32), 256, 0, stream>>>(roffD, eidD, apermB, aw1, ab1, aw2, ab2,
                                          attn, swD, n);
  // src-half via attn-row gather (linearized MLP) + t_relu
  k_sumw_tr<<<CDIV(n, 32), 256, 0, stream>>>(roffS, eidS, attn, swD, aw1, ab1, aw2, ab2,
                                             tw1, tb1, tr, n);

  // message aggregation + e_emb + BN partials
  k_msg<<<gridMsg, 256, 0, stream>>>(srcD, roffD, apermB, featbf, tr, tw2, tb2, gat_bias,
                                     hout, partial, n);
  // BN reduce + finalize + elementwise epilogue, single launch
  k_redfinal<<<nblkR, 256, 0, stream>>>(partial, bnsum, gamma, beta, h_in, hout,
                                        mu, scale, meta + 399, meta + 396,
                                        gridMsg, n, nblkR);
}

// Round 9
// 323.671 us; speedup vs baseline: 1.1197x; 1.1197x over previous
//
#include <hip/hip_runtime.h>
#include <math.h>

#define CDIV(a,b) (((a)+(b)-1)/(b))
#define SEGCAP 768  // max edges per 32-node group in LDS fast path (mean 384)

typedef unsigned short ushort_t;

__device__ __forceinline__ ushort_t f2bf(float x) {
  unsigned u = __float_as_uint(x);
  unsigned r = (u + 0x7FFFu + ((u >> 16) & 1u)) >> 16;
  return (ushort_t)r;
}
__device__ __forceinline__ float bf2f(ushort_t s) {
  return __uint_as_float(((unsigned)s) << 16);
}

typedef __attribute__((ext_vector_type(8))) short bf16x8;
typedef __attribute__((ext_vector_type(4))) float f32x4;

// ---------------------------------------------------------------------------
// K1 (MFMA): feat = h @ fc_w.T via split-bf16 (hi+lo). el/er via an EXTRA
// 16-col MFMA tile: B_e[k][j] = wl[k][j] (j<8) / wr[k][j-8], where
// wl = fc_w.T·al blockdiag (computed per block in fp32, split to bf16 LDS).
// Wave wv computes the el/er tile for its own 16-row tile -- replaces the
// 256-shfl/lane butterfly epilogue.
// ---------------------------------------------------------------------------
__global__ __launch_bounds__(256) void k_gemm(const float* __restrict__ hm,
                                              const float* __restrict__ w,
                                              const float* __restrict__ al,
                                              const float* __restrict__ ar,
                                              ushort_t* __restrict__ featbf,
                                              float* __restrict__ el,
                                              float* __restrict__ er, int n) {
  __shared__ ushort_t Ahi[64 * 128];          // 16KB, XOR-swizzled rows
  __shared__ ushort_t Alo[64 * 128];          // 16KB
  __shared__ ushort_t BeL[4][4][16][16];      // 8KB: [kt][lg][lr][8 hi | 8 lo]
  const int t = threadIdx.x;
  const int wv = t >> 6;   // wave 0..3
  const int l = t & 63;    // lane
  const int lr = l & 15;   // row-in-tile (A) / col-in-tile (B,C)
  const int lg = l >> 4;   // k-group 0..3

  // ---- phase 0: wlr[k][j] fp32 in LDS (reuse Ahi region as float buffer) ----
  float* wlr = (float*)Ahi;  // [128][16]
  {
    int k = t >> 1, j0 = (t & 1) * 8;
    const float* av = (t & 1) ? ar : al;
    float out[8];
#pragma unroll
    for (int jh = 0; jh < 8; ++jh) out[jh] = 0.f;
#pragma unroll
    for (int jh = 0; jh < 8; ++jh) {
#pragma unroll
      for (int d = 0; d < 16; ++d) {
        out[jh] += w[(size_t)(jh * 16 + d) * 128 + k] * av[jh * 16 + d];
      }
    }
#pragma unroll
    for (int jh = 0; jh < 8; ++jh) wlr[k * 16 + j0 + jh] = out[jh];
  }
  __syncthreads();
  // ---- phase 1: one wave extracts+splits B_e into BeL ----
  if (t < 64) {
#pragma unroll
    for (int kt = 0; kt < 4; ++kt) {
      float xs[8];
#pragma unroll
      for (int i = 0; i < 8; ++i) xs[i] = wlr[(kt * 32 + lg * 8 + i) * 16 + lr];
#pragma unroll
      for (int i = 0; i < 8; ++i) {
        unsigned u = __float_as_uint(xs[i]);
        BeL[kt][lg][lr][i] = (ushort_t)(u >> 16);
        float resid = xs[i] - __uint_as_float(u & 0xFFFF0000u);
        BeL[kt][lg][lr][8 + i] = (ushort_t)(__float_as_uint(resid) >> 16);
      }
    }
  }

  // ---- B fragments (feat cols): fc_w split to bf16 hi/lo in registers ----
  bf16x8 Bhi[4][2], Blo[4][2];
#pragma unroll
  for (int ct = 0; ct < 2; ++ct) {
    const float* wr = w + (size_t)(32 * wv + ct * 16 + lr) * 128;
#pragma unroll
    for (int kt = 0; kt < 4; ++kt) {
      const float* wp = wr + kt * 32 + lg * 8;
      float4 v0 = *(const float4*)wp;
      float4 v1 = *(const float4*)(wp + 4);
      float xs[8] = {v0.x, v0.y, v0.z, v0.w, v1.x, v1.y, v1.z, v1.w};
      bf16x8 hi, lo;
#pragma unroll
      for (int i = 0; i < 8; ++i) {
        unsigned u = __float_as_uint(xs[i]);
        hi[i] = (short)(u >> 16);
        float resid = xs[i] - __uint_as_float(u & 0xFFFF0000u);
        lo[i] = (short)(__float_as_uint(resid) >> 16);
      }
      Bhi[kt][ct] = hi;
      Blo[kt][ct] = lo;
    }
  }
  __syncthreads();  // BeL ready; wlr region free for A staging

  const int base = blockIdx.x * 64;
#pragma unroll
  for (int r8 = 0; r8 < 8; ++r8) {
    int f = t + 256 * r8;
    int row = f >> 5, c4 = f & 31;
    int nidx = base + row;
    float4 v = make_float4(0.f, 0.f, 0.f, 0.f);
    if (nidx < n) v = ((const float4*)hm)[(size_t)nidx * 32 + c4];
    unsigned ux = __float_as_uint(v.x), uy = __float_as_uint(v.y);
    unsigned uz = __float_as_uint(v.z), uw = __float_as_uint(v.w);
    unsigned hi0 = (ux >> 16) | (uy & 0xFFFF0000u);
    unsigned hi1 = (uz >> 16) | (uw & 0xFFFF0000u);
    float rx = v.x - __uint_as_float(ux & 0xFFFF0000u);
    float ry = v.y - __uint_as_float(uy & 0xFFFF0000u);
    float rz = v.z - __uint_as_float(uz & 0xFFFF0000u);
    float rw = v.w - __uint_as_float(uw & 0xFFFF0000u);
    unsigned lo0 = (__float_as_uint(rx) >> 16) | (__float_as_uint(ry) & 0xFFFF0000u);
    unsigned lo1 = (__float_as_uint(rz) >> 16) | (__float_as_uint(rw) & 0xFFFF0000u);
    int uidx = row * 128 + ((c4 * 4) ^ ((row & 7) << 3));
    *(uint2*)&Ahi[uidx] = make_uint2(hi0, hi1);
    *(uint2*)&Alo[uidx] = make_uint2(lo0, lo1);
  }
  __syncthreads();

  f32x4 acc[4][2];
  f32x4 acce = (f32x4){0.f, 0.f, 0.f, 0.f};
#pragma unroll
  for (int mt = 0; mt < 4; ++mt)
#pragma unroll
    for (int ct = 0; ct < 2; ++ct) acc[mt][ct] = (f32x4){0.f, 0.f, 0.f, 0.f};

#pragma unroll
  for (int mt = 0; mt < 4; ++mt) {
    const int row = mt * 16 + lr;
    const int rbase = row * 128;
    const int swz = (row & 7) << 3;
#pragma unroll
    for (int kt = 0; kt < 4; ++kt) {
      const int k0 = (kt * 32 + lg * 8) ^ swz;
      bf16x8 ah = *(const bf16x8*)&Ahi[rbase + k0];
      bf16x8 ao = *(const bf16x8*)&Alo[rbase + k0];
#pragma unroll
      for (int ct = 0; ct < 2; ++ct) {
        acc[mt][ct] = __builtin_amdgcn_mfma_f32_16x16x32_bf16(ah, Bhi[kt][ct], acc[mt][ct], 0, 0, 0);
        acc[mt][ct] = __builtin_amdgcn_mfma_f32_16x16x32_bf16(ah, Blo[kt][ct], acc[mt][ct], 0, 0, 0);
        acc[mt][ct] = __builtin_amdgcn_mfma_f32_16x16x32_bf16(ao, Bhi[kt][ct], acc[mt][ct], 0, 0, 0);
      }
      if (mt == wv) {  // wave-uniform: this wave's el/er row-tile
        bf16x8 behi = *(const bf16x8*)&BeL[kt][lg][lr][0];
        bf16x8 belo = *(const bf16x8*)&BeL[kt][lg][lr][8];
        acce = __builtin_amdgcn_mfma_f32_16x16x32_bf16(ah, behi, acce, 0, 0, 0);
        acce = __builtin_amdgcn_mfma_f32_16x16x32_bf16(ah, belo, acce, 0, 0, 0);
        acce = __builtin_amdgcn_mfma_f32_16x16x32_bf16(ao, behi, acce, 0, 0, 0);
      }
    }
  }

  // ---- el/er epilogue: C layout col=lr (j), row=lg*4+rg ----
#pragma unroll
  for (int rg = 0; rg < 4; ++rg) {
    int node = base + wv * 16 + lg * 4 + rg;
    if (node < n) {
      if (lr < 8) el[(size_t)node * 8 + lr] = acce[rg];
      else        er[(size_t)node * 8 + (lr - 8)] = acce[rg];
    }
  }

  // ---- featbf: scatter acc -> LDS [row][col] bf16, then full-line stores ----
  __syncthreads();
#pragma unroll
  for (int mt = 0; mt < 4; ++mt)
#pragma unroll
    for (int ct = 0; ct < 2; ++ct) {
      const int colw = 32 * wv + ct * 16 + lr;
#pragma unroll
      for (int rg = 0; rg < 4; ++rg) {
        int row = mt * 16 + lg * 4 + rg;
        Ahi[row * 128 + colw] = f2bf(acc[mt][ct][rg]);
      }
    }
  __syncthreads();
#pragma unroll
  for (int r4 = 0; r4 < 4; ++r4) {
    int f = t + 256 * r4;
    int row = f >> 4, q = f & 15;
    int node = base + row;
    if (node < n)
      ((uint4*)featbf)[(size_t)node * 16 + q] = *(const uint4*)&Ahi[row * 128 + q * 8];
  }
}

// ---------------------------------------------------------------------------
// K-sort (fused hist + scan + scatter): 147 blocks <= 256 CUs -> all resident
// -> ticket/flag spin safe. All same-kernel cross-block handoffs are ATOMIC;
// threadfence release/acquire around the flag.
// meta layout (1200 uints), all ranges DISJOINT:
//   histD@0..195  histS@200..395  (396 free)  sortflag@397
//   sortticket@398  redticket@399  curbD@400..595  curbS@600..795
//   bktoffD@800..996  bktoffS@1000..1196
// ---------------------------------------------------------------------------
__global__ __launch_bounds__(256) void k_sort(const int* __restrict__ src,
                                              const int* __restrict__ dst,
                                              unsigned* __restrict__ meta,
                                              unsigned* __restrict__ roffD,
                                              unsigned* __restrict__ roffS,
                                              uint2* __restrict__ recD,
                                              unsigned* __restrict__ recS,
                                              int nbkt, int n, int e, int nblk) {
  __shared__ unsigned lhD[256], lhS[256], lcD[256], lcS[256], s[256];
  __shared__ unsigned tk;
  int t = threadIdx.x;
  lhD[t] = 0; lhS[t] = 0;
  __syncthreads();
  int base = blockIdx.x * 4096;
  for (int k = 0; k < 16; ++k) {
    int i = base + t + 256 * k;
    if (i < e) {
      atomicAdd(&lhD[((unsigned)dst[i]) >> 8], 1u);
      atomicAdd(&lhS[((unsigned)src[i]) >> 8], 1u);
    }
  }
  __syncthreads();
  if (t < nbkt) {
    if (lhD[t]) atomicAdd(&meta[t], lhD[t]);
    if (lhS[t]) atomicAdd(&meta[200 + t], lhS[t]);
  }
  __threadfence();
  __syncthreads();
  if (t == 0) tk = atomicAdd(&meta[398], 1u);
  __syncthreads();
  if (tk == (unsigned)(nblk - 1)) {
    for (int g = 0; g < 2; ++g) {
      unsigned v = (t < nbkt) ? atomicAdd(&meta[g * 200 + t], 0u) : 0u;
      s[t] = v;
      __syncthreads();
      for (int off = 1; off < 256; off <<= 1) {
        unsigned x = (t >= off) ? s[t - off] : 0u;
        __syncthreads();
        s[t] += x;
        __syncthreads();
      }
      unsigned excl = s[t] - v;
      if (t < nbkt) {
        meta[800 + g * 200 + t] = excl;              // read by NEXT kernel (k_finB)
        atomicExch(&meta[400 + g * 200 + t], excl);  // read SAME-kernel: atomic
      }
      if (t == 0) meta[800 + g * 200 + nbkt] = (unsigned)e;
      __syncthreads();
    }
    if (t == 0) { roffD[n] = (unsigned)e; roffS[n] = (unsigned)e; }
    __threadfence();
    __syncthreads();
    if (t == 0) atomicExch(&meta[397], 1u);
  }
  if (t == 0) {
    while (atomicAdd(&meta[397], 0u) == 0u) __builtin_amdgcn_s_sleep(16);
  }
  __syncthreads();
  __threadfence();  // acquire
  if (t < nbkt) {
    lcD[t] = lhD[t] ? atomicAdd(&meta[400 + t], lhD[t]) : 0u;
    lcS[t] = lhS[t] ? atomicAdd(&meta[600 + t], lhS[t]) : 0u;
  }
  __syncthreads();
  for (int k = 0; k < 16; ++k) {
    int i = base + t + 256 * k;
    if (i < e) {
      unsigned d2 = (unsigned)dst[i], s2 = (unsigned)src[i];
      unsigned pD = atomicAdd(&lcD[d2 >> 8], 1u);
      recD[pD] = make_uint2(((d2 & 255u) << 16) | s2, (unsigned)i);
      unsigned pS = atomicAdd(&lcS[s2 >> 8], 1u);
      recS[pS] = ((s2 & 255u) << 24) | (unsigned)i;
    }
  }
}

// ---------------------------------------------------------------------------
// K-finB (combined dst+src fine placement, grid = 2*nbkt): b<nbkt -> dst path
// (+ fused edge-e leaky_relu -> bf16 aperm); else src path (eidS payload).
// Pure per-block work -- no cross-block sync.
// ---------------------------------------------------------------------------
__global__ __launch_bounds__(256) void k_finB(const uint2* __restrict__ recD,
                                              const unsigned* __restrict__ recS,
                                              const unsigned* __restrict__ meta,
                                              const float* __restrict__ el,
                                              const float* __restrict__ er,
                                              unsigned* __restrict__ roffD,
                                              unsigned* __restrict__ roffS,
                                              ushort_t* __restrict__ apermB,
                                              int* __restrict__ srcD,
                                              unsigned* __restrict__ eidD,
                                              unsigned* __restrict__ eidS,
                                              int nbkt, int n) {
  __shared__ float erL[256 * 8];
  __shared__ unsigned cnt1[256], cnt2[256], sc[256];
  int t = threadIdx.x;
  int b = blockIdx.x;
  if (b < nbkt) {
    const unsigned* bktoff = meta + 800;
    unsigned b0 = bktoff[b], b1 = bktoff[b + 1];
    int nb0 = b << 8;
    for (int k = 0; k < 8; ++k) {
      int idx = t + 256 * k;
      int node = nb0 + (idx >> 3);
      erL[idx] = (node < n) ? er[(size_t)nb0 * 8 + idx] : 0.f;
    }
    cnt1[t] = 0;
    __syncthreads();
    for (unsigned j = b0 + t; j < b1; j += 256) {
      unsigned nodeLoc = (recD[j].x >> 16) & 255u;
      atomicAdd(&cnt1[nodeLoc], 1u);
    }
    __syncthreads();
    unsigned v = cnt1[t];
    sc[t] = v;
    __syncthreads();
    for (int off = 1; off < 256; off <<= 1) {
      unsigned x = (t >= off) ? sc[t - off] : 0u;
      __syncthreads();
      sc[t] += x;
      __syncthreads();
    }
    unsigned excl = sc[t] - v;
    int node = nb0 + t;
    if (node < n) roffD[node] = b0 + excl;
    cnt2[t] = b0 + excl;
    __syncthreads();
    for (unsigned j = b0 + t; j < b1; j += 256) {
      uint2 r = recD[j];
      unsigned nodeLoc = (r.x >> 16) & 255u;
      unsigned srcv = r.x & 0xFFFFu;
      unsigned pos = atomicAdd(&cnt2[nodeLoc], 1u);
      float4 a0 = *(const float4*)&el[(size_t)srcv * 8];
      float4 a1 = *(const float4*)&el[(size_t)srcv * 8 + 4];
      const float* eb = &erL[nodeLoc * 8];
      float ev[8] = {a0.x + eb[0], a0.y + eb[1], a0.z + eb[2], a0.w + eb[3],
                     a1.x + eb[4], a1.y + eb[5], a1.z + eb[6], a1.w + eb[7]};
#pragma unroll
      for (int h2 = 0; h2 < 8; ++h2) ev[h2] = ev[h2] > 0.f ? ev[h2] : 0.2f * ev[h2];
      unsigned q0 = (unsigned)f2bf(ev[0]) | ((unsigned)f2bf(ev[1]) << 16);
      unsigned q1 = (unsigned)f2bf(ev[2]) | ((unsigned)f2bf(ev[3]) << 16);
      unsigned q2 = (unsigned)f2bf(ev[4]) | ((unsigned)f2bf(ev[5]) << 16);
      unsigned q3 = (unsigned)f2bf(ev[6]) | ((unsigned)f2bf(ev[7]) << 16);
      *(uint4*)&apermB[(size_t)pos * 8] = make_uint4(q0, q1, q2, q3);
      srcD[pos] = (int)srcv;
      eidD[pos] = r.y;
    }
  } else {
    int bs = b - nbkt;
    const unsigned* bktoff = meta + 1000;
    unsigned b0 = bktoff[bs], b1 = bktoff[bs + 1];
    int nb0 = bs << 8;
    cnt1[t] = 0;
    __syncthreads();
    for (unsigned j = b0 + t; j < b1; j += 256) {
      unsigned nodeLoc = recS[j] >> 24;
      atomicAdd(&cnt1[nodeLoc], 1u);
    }
    __syncthreads();
    unsigned v = cnt1[t];
    sc[t] = v;
    __syncthreads();
    for (int off = 1; off < 256; off <<= 1) {
      unsigned x = (t >= off) ? sc[t - off] : 0u;
      __syncthreads();
      sc[t] += x;
      __syncthreads();
    }
    unsigned excl = sc[t] - v;
    int node = nb0 + t;
    if (node < n) roffS[node] = b0 + excl;
    cnt2[t] = b0 + excl;
    __syncthreads();
    for (unsigned j = b0 + t; j < b1; j += 256) {
      unsigned r = recS[j];
      unsigned nodeLoc = r >> 24;
      unsigned pos = atomicAdd(&cnt2[nodeLoc], 1u);
      eidS[pos] = r & 0x00FFFFFFu;
    }
  }
}

// ---------------------------------------------------------------------------
// K-attn (fused): softmax -> dst-half R-accumulation (linearity: sum_w =
// deg*(1-B2) - W2·R) -> per-edge writeback. Serial per-(node,h) loops are
// pure LDS+VALU; normalize pass folded into MLP pass via inv-prescaled W1.
// ---------------------------------------------------------------------------
__global__ __launch_bounds__(256) void k_attn(const unsigned* __restrict__ roffD,
                                              const unsigned* __restrict__ eidD,
                                              ushort_t* __restrict__ apermB,
                                              const float* __restrict__ aw1,
                                              const float* __restrict__ ab1,
                                              const float* __restrict__ aw2,
                                              const float* __restrict__ ab2,
                                              float* __restrict__ attn,
                                              float* __restrict__ swD, int n) {
  __shared__ float aL[SEGCAP * 8];
  __shared__ float W1[64], W2[64], B1[8], B2[8];
  __shared__ unsigned nb_[33];
  int t = threadIdx.x;
  if (t < 64) { W1[t] = aw1[t]; W2[t] = aw2[t]; }
  else if (t < 72) { B1[t - 64] = ab1[t - 64]; B2[t - 64] = ab2[t - 64]; }
  int g0 = blockIdx.x * 32;
  if (t < 33) {
    int node = g0 + t;
    nb_[t] = roffD[node < n ? node : n];
  }
  __syncthreads();
  unsigned b0 = nb_[0], b1 = nb_[32];
  unsigned count = b1 - b0;
  int ln = t >> 3, h = t & 7;
  int node = g0 + ln;
  const int l = t & 63, gbl = l & 56;
  if (count <= SEGCAP) {
    const unsigned* ap32 = (const unsigned*)apermB + (size_t)b0 * 4;
    for (unsigned k = t; k < count * 4; k += 256) {
      unsigned pk = ap32[k];
      aL[k * 2] = bf2f((ushort_t)(pk & 0xFFFFu));
      aL[k * 2 + 1] = bf2f((ushort_t)(pk >> 16));
    }
    __syncthreads();
    unsigned s0 = nb_[ln] - b0, s1 = nb_[ln + 1] - b0;
    float inv = 0.f;
    if (node < n) {
      float ssum = 0.f;
      for (unsigned j = s0; j < s1; ++j) {
        float ex = expf(aL[j * 8 + h]);
        aL[j * 8 + h] = ex;
        ssum += ex;
      }
      inv = ssum > 0.f ? 1.f / ssum : 0.f;
    }
    __syncthreads();
    float w1m[8];
#pragma unroll
    for (int m = 0; m < 8; ++m) w1m[m] = W1[h * 8 + m] * __shfl(inv, gbl | m);
    if (node < n) {
      float R = 0.f;
      for (unsigned j = s0; j < s1; ++j) {
        const float* a = &aL[j * 8];
        float acc = B1[h];
#pragma unroll
        for (int m = 0; m < 8; ++m) acc += a[m] * w1m[m];
        acc = acc > 0.f ? acc : 0.f;
        R += acc;
        aL[j * 8 + h] = a[h] * inv;  // normalize own slot (folded pass)
      }
      float sv = (float)(s1 - s0) * (1.f - B2[h]);
#pragma unroll
      for (int r = 0; r < 8; ++r) {
        int jj = (h + r) & 7;
        float Rj = __shfl(R, gbl | jj);
        sv -= W2[h * 8 + jj] * Rj;
      }
      swD[(size_t)node * 8 + h] = sv;
    }
    __syncthreads();
    for (unsigned eL = t; eL < count; eL += 256) {
      const float* a = &aL[eL * 8];
      unsigned ee = eidD[b0 + eL];
      float4* op = (float4*)&attn[(size_t)ee * 8];
      op[0] = make_float4(a[0], a[1], a[2], a[3]);
      op[1] = make_float4(a[4], a[5], a[6], a[7]);
      unsigned q0 = (unsigned)f2bf(a[0]) | ((unsigned)f2bf(a[1]) << 16);
      unsigned q1 = (unsigned)f2bf(a[2]) | ((unsigned)f2bf(a[3]) << 16);
      unsigned q2 = (unsigned)f2bf(a[4]) | ((unsigned)f2bf(a[5]) << 16);
      unsigned q3 = (unsigned)f2bf(a[6]) | ((unsigned)f2bf(a[7]) << 16);
      *(uint4*)&apermB[(size_t)(b0 + eL) * 8] = make_uint4(q0, q1, q2, q3);
    }
  } else {
    unsigned sb = nb_[ln], se = nb_[ln + 1];
    if (node < n) {
      float s = 0.f;
      for (unsigned j = sb; j < se; ++j) s += expf(bf2f(apermB[(size_t)j * 8 + h]));
      float inv = s > 0.f ? 1.f / s : 0.f;
      for (unsigned j = sb; j < se; ++j) {
        size_t p = (size_t)j * 8 + h;
        apermB[p] = f2bf(expf(bf2f(apermB[p])) * inv);
      }
    }
    __syncthreads();
    if (node < n) {
      float R = 0.f;
      for (unsigned j = sb; j < se; ++j) {
        float a[8];
#pragma unroll
        for (int m = 0; m < 8; ++m) a[m] = bf2f(apermB[(size_t)j * 8 + m]);
        float acc = B1[h];
#pragma unroll
        for (int m = 0; m < 8; ++m) acc += a[m] * W1[h * 8 + m];
        acc = acc > 0.f ? acc : 0.f;
        R += acc;
      }
      float sv = (float)(se - sb) * (1.f - B2[h]);
#pragma unroll
      for (int r = 0; r < 8; ++r) {
        int jj = (h + r) & 7;
        float Rj = __shfl(R, gbl | jj);
        sv -= W2[h * 8 + jj] * Rj;
      }
      swD[(size_t)node * 8 + h] = sv;
    }
    for (unsigned eL = t; eL < count; eL += 256) {
      unsigned j = b0 + eL;
      float a[8];
#pragma unroll
      for (int m = 0; m < 8; ++m) a[m] = bf2f(apermB[(size_t)j * 8 + m]);
      unsigned ee = eidD[j];
      float4* op = (float4*)&attn[(size_t)ee * 8];
      op[0] = make_float4(a[0], a[1], a[2], a[3]);
      op[1] = make_float4(a[4], a[5], a[6], a[7]);
    }
  }
}

// K5: src-half sum_w via fp32 attn-row gather (eidS coalesced; same-row lanes
// wave-merged; 4-wide unrolled gathers). Lane h computes only hidden unit h.
__global__ __launch_bounds__(256) void k_sumw_tr(const unsigned* __restrict__ roffS,
                                                 const unsigned* __restrict__ eidS,
                                                 const float* __restrict__ attn,
                                                 const float* __restrict__ swD,
                                                 const float* __restrict__ aw1,
                                                 const float* __restrict__ ab1,
                                                 const float* __restrict__ aw2,
                                                 const float* __restrict__ ab2,
                                                 const float* __restrict__ tw1,
                                                 const float* __restrict__ tb1,
                                                 float* __restrict__ tr, int n) {
  __shared__ float sw[32][9];
  __shared__ float W1[64], W2[64], T1[64], B1[8], B2[8], TB[8];
  int t = threadIdx.x;
  if (t < 64) { W1[t] = aw1[t]; W2[t] = aw2[t]; T1[t] = tw1[t]; }
  else if (t < 72) { B1[t - 64] = ab1[t - 64]; B2[t - 64] = ab2[t - 64]; TB[t - 64] = tb1[t - 64]; }
  __syncthreads();
  int ln = t >> 3, h = t & 7;
  int node = blockIdx.x * 32 + ln;
  const int gbl = (t & 63) & 56;
  float w1r[8];
#pragma unroll
  for (int m = 0; m < 8; ++m) w1r[m] = W1[h * 8 + m];
  const float B1h = B1[h];
  if (node < n) {
    unsigned b = roffS[node], en = roffS[node + 1];
    float R = 0.f;
    unsigned j = b;
    for (; j + 4 <= en; j += 4) {
      unsigned e0 = eidS[j], e1 = eidS[j + 1], e2 = eidS[j + 2], e3 = eidS[j + 3];
      const float* p0 = &attn[(size_t)e0 * 8];
      const float* p1 = &attn[(size_t)e1 * 8];
      const float* p2 = &attn[(size_t)e2 * 8];
      const float* p3 = &attn[(size_t)e3 * 8];
      float4 x00 = *(const float4*)p0, x01 = *(const float4*)(p0 + 4);
      float4 x10 = *(const float4*)p1, x11 = *(const float4*)(p1 + 4);
      float4 x20 = *(const float4*)p2, x21 = *(const float4*)(p2 + 4);
      float4 x30 = *(const float4*)p3, x31 = *(const float4*)(p3 + 4);
      float a0 = B1h + x00.x * w1r[0] + x00.y * w1r[1] + x00.z * w1r[2] + x00.w * w1r[3]
                     + x01.x * w1r[4] + x01.y * w1r[5] + x01.z * w1r[6] + x01.w * w1r[7];
      float a1 = B1h + x10.x * w1r[0] + x10.y * w1r[1] + x10.z * w1r[2] + x10.w * w1r[3]
                     + x11.x * w1r[4] + x11.y * w1r[5] + x11.z * w1r[6] + x11.w * w1r[7];
      float a2 = B1h + x20.x * w1r[0] + x20.y * w1r[1] + x20.z * w1r[2] + x20.w * w1r[3]
                     + x21.x * w1r[4] + x21.y * w1r[5] + x21.z * w1r[6] + x21.w * w1r[7];
      float a3 = B1h + x30.x * w1r[0] + x30.y * w1r[1] + x30.z * w1r[2] + x30.w * w1r[3]
                     + x31.x * w1r[4] + x31.y * w1r[5] + x31.z * w1r[6] + x31.w * w1r[7];
      R += (a0 > 0.f ? a0 : 0.f) + (a1 > 0.f ? a1 : 0.f) +
           (a2 > 0.f ? a2 : 0.f) + (a3 > 0.f ? a3 : 0.f);
    }
    for (; j < en; ++j) {
      unsigned e0 = eidS[j];
      const float* p0 = &attn[(size_t)e0 * 8];
      float4 x00 = *(const float4*)p0, x01 = *(const float4*)(p0 + 4);
      float a0 = B1h + x00.x * w1r[0] + x00.y * w1r[1] + x00.z * w1r[2] + x00.w * w1r[3]
                     + x01.x * w1r[4] + x01.y * w1r[5] + x01.z * w1r[6] + x01.w * w1r[7];
      R += a0 > 0.f ? a0 : 0.f;
    }
    float sv = swD[(size_t)node * 8 + h] + (float)(en - b) * (1.f - B2[h]);
#pragma unroll
    for (int r = 0; r < 8; ++r) {
      int jj = (h + r) & 7;
      float Rj = __shfl(R, gbl | jj);
      sv -= W2[h * 8 + jj] * Rj;
    }
    sw[ln][h] = sv;
  }
  __syncthreads();
  if (node < n) {
    float acc = TB[h];
#pragma unroll
    for (int m = 0; m < 8; ++m) acc += sw[ln][m] * T1[h * 8 + m];
    tr[(size_t)node * 8 + h] = acc > 0.f ? acc : 0.f;
  }
}

// K-msg (fused e_emb + BN stats): r1 form (measured 43.2us @ occ 54% --
// deeper pipelines r2/r3 both regressed; gather stream is occupancy/TLP-fed).
__global__ __launch_bounds__(256) void k_msg(const int* __restrict__ srcD,
                                             const unsigned* __restrict__ roff,
                                             const ushort_t* __restrict__ apermB,
                                             const ushort_t* __restrict__ featbf,
                                             const float* __restrict__ tr,
                                             const float* __restrict__ tw2,
                                             const float* __restrict__ tb2,
                                             const float* __restrict__ gat_bias,
                                             float* __restrict__ hout,
                                             float* __restrict__ partial, int n) {
  __shared__ float bn1[4][128], bn2[4][128];
  int t = threadIdx.x;
  int w = t >> 6, lane = t & 63;
  int col = lane * 2;
  int hh = lane >> 3;
  float w2a[8], w2b[8];
#pragma unroll
  for (int j = 0; j < 8; ++j) { w2a[j] = tw2[col * 8 + j]; w2b[j] = tw2[(col + 1) * 8 + j]; }
  float biasA = tb2[col] + gat_bias[col];
  float biasB = tb2[col + 1] + gat_bias[col + 1];
  float s1a = 0.f, s1b = 0.f, s2a = 0.f, s2b = 0.f;
  int nodeBase = blockIdx.x * 16 + w * 4;
  for (int ni = 0; ni < 4; ++ni) {
    int node = nodeBase + ni;
    if (node >= n) break;
    unsigned b = roff[node], en = roff[node + 1];
    float x0 = 0.f, x1 = 0.f;
    unsigned j = b;
    for (; j + 4 <= en; j += 4) {
      int sa = srcD[j], sb = srcD[j + 1], sc2 = srcD[j + 2], sd = srcD[j + 3];
      float av0 = bf2f(apermB[(size_t)j * 8 + hh]);
      float av1 = bf2f(apermB[(size_t)(j + 1) * 8 + hh]);
      float av2 = bf2f(apermB[(size_t)(j + 2) * 8 + hh]);
      float av3 = bf2f(apermB[(size_t)(j + 3) * 8 + hh]);
      unsigned p0 = *(const unsigned*)&featbf[(size_t)sa * 128 + col];
      unsigned p1 = *(const unsigned*)&featbf[(size_t)sb * 128 + col];
      unsigned p2 = *(const unsigned*)&featbf[(size_t)sc2 * 128 + col];
      unsigned p3 = *(const unsigned*)&featbf[(size_t)sd * 128 + col];
      x0 += bf2f((ushort_t)(p0 & 0xFFFFu)) * av0 + bf2f((ushort_t)(p1 & 0xFFFFu)) * av1 +
            bf2f((ushort_t)(p2 & 0xFFFFu)) * av2 + bf2f((ushort_t)(p3 & 0xFFFFu)) * av3;
      x1 += bf2f((ushort_t)(p0 >> 16)) * av0 + bf2f((ushort_t)(p1 >> 16)) * av1 +
            bf2f((ushort_t)(p2 >> 16)) * av2 + bf2f((ushort_t)(p3 >> 16)) * av3;
    }
    for (; j < en; ++j) {
      int sa = srcD[j];
      float av0 = bf2f(apermB[(size_t)j * 8 + hh]);
      unsigned p0 = *(const unsigned*)&featbf[(size_t)sa * 128 + col];
      x0 += bf2f((ushort_t)(p0 & 0xFFFFu)) * av0;
      x1 += bf2f((ushort_t)(p0 >> 16)) * av0;
    }
    const float* trn = &tr[(size_t)node * 8];
    float emA = biasA, emB = biasB;
#pragma unroll
    for (int jj = 0; jj < 8; ++jj) {
      float tv = trn[jj];
      emA += tv * w2a[jj];
      emB += tv * w2b[jj];
    }
    float v0 = x0 + emA, v1 = x1 + emB;
    *(float2*)&hout[(size_t)node * 128 + col] = make_float2(v0, v1);
    s1a += v0; s1b += v1; s2a += v0 * v0; s2b += v1 * v1;
  }
  bn1[w][col] = s1a; bn1[w][col + 1] = s1b;
  bn2[w][col] = s2a; bn2[w][col + 1] = s2b;
  __syncthreads();
  int f = t & 127;
  float acc;
  if (t < 128) acc = bn1[0][f] + bn1[1][f] + bn1[2][f] + bn1[3][f];
  else         acc = bn2[0][f] + bn2[1][f] + bn2[2][f] + bn2[3][f];
  partial[(size_t)blockIdx.x * 256 + t] = acc;
}

// Reduce per-block BN partials + fused last-block finalize (mu/scale).
// (r5-proven form; mu/scale consumed by the NEXT kernel -> plain stores OK.)
__global__ __launch_bounds__(256) void k_red(const float* __restrict__ partial,
                                             float* __restrict__ bnacc,
                                             const float* __restrict__ gamma,
                                             float* __restrict__ mu,
                                             float* __restrict__ scale,
                                             unsigned* __restrict__ ticket,
                                             int rows, int n, int nblk) {
  __shared__ unsigned isLast;
  int t = threadIdx.x;
  int r0 = blockIdx.x * 13, r1 = r0 + 13;
  if (r1 > rows) r1 = rows;
  float acc = 0.f;
  for (int r = r0; r < r1; ++r) acc += partial[(size_t)r * 256 + t];
  if (r0 < r1) atomicAdd(&bnacc[t], acc);
  __threadfence();
  if (t == 0) isLast = (atomicAdd(ticket, 1u) == (unsigned)(nblk - 1)) ? 1u : 0u;
  __syncthreads();
  if (isLast && t < 128) {
    float sm = atomicAdd(&bnacc[t], 0.f);         // coherent reads
    float sq = atomicAdd(&bnacc[128 + t], 0.f);
    float m = sm / (float)n;
    float v = sq / (float)n - m * m;
    mu[t] = m;
    scale[t] = rsqrtf(v + 1e-5f) * gamma[t];
  }
}

// K7: out = h_in + elu((x - mu)*scale + beta)  -- full grid, BW-bound.
__global__ void k_final(const float* __restrict__ hin, float* __restrict__ hout,
                        const float* __restrict__ mu, const float* __restrict__ scale,
                        const float* __restrict__ beta, int total4) {
  int i = blockIdx.x * blockDim.x + threadIdx.x;
  if (i >= total4) return;
  int c = (i & 31) * 4;
  float4 x = ((const float4*)hout)[i];
  float4 m4 = *(const float4*)&mu[c];
  float4 s4 = *(const float4*)&scale[c];
  float4 b4 = *(const float4*)&beta[c];
  float4 hi = ((const float4*)hin)[i];
  float y0 = (x.x - m4.x) * s4.x + b4.x;
  float y1 = (x.y - m4.y) * s4.y + b4.y;
  float y2 = (x.z - m4.z) * s4.z + b4.z;
  float y3 = (x.w - m4.w) * s4.w + b4.w;
  y0 = y0 > 0.f ? y0 : expm1f(y0);
  y1 = y1 > 0.f ? y1 : expm1f(y1);
  y2 = y2 > 0.f ? y2 : expm1f(y2);
  y3 = y3 > 0.f ? y3 : expm1f(y3);
  float4 o = make_float4(hi.x + y0, hi.y + y1, hi.z + y2, hi.w + y3);
  ((float4*)hout)[i] = o;
}

extern "C" void kernel_launch(void* const* d_in, const int* in_sizes, int n_in,
                              void* d_out, int out_size, void* d_ws, size_t ws_size,
                              hipStream_t stream) {
  const float* h_in     = (const float*)d_in[0];
  const int*   esrc     = (const int*)d_in[1];
  const int*   edst     = (const int*)d_in[2];
  const float* fc_w     = (const float*)d_in[4];
  const float* attn_l   = (const float*)d_in[5];
  const float* attn_r   = (const float*)d_in[6];
  const float* gat_bias = (const float*)d_in[7];
  const float* aw1      = (const float*)d_in[8];
  const float* ab1      = (const float*)d_in[9];
  const float* aw2      = (const float*)d_in[10];
  const float* ab2      = (const float*)d_in[11];
  const float* tw1      = (const float*)d_in[12];
  const float* tb1      = (const float*)d_in[13];
  const float* tw2      = (const float*)d_in[14];
  const float* tb2      = (const float*)d_in[15];
  const float* gamma    = (const float*)d_in[16];
  const float* beta     = (const float*)d_in[17];

  const int n = in_sizes[0] / 128;  // 50000
  const int e = in_sizes[1];        // 600000
  const int nbkt = CDIV(n, 256);    // 196
  const int gridMsg = CDIV(n, 16);  // 3125
  const int nblkE = CDIV(e, 4096);  // 147  (<= 256 CUs: k_sort spin safe)
  const int nblkR = CDIV(gridMsg, 13);  // 241

  float* ws = (float*)d_ws;
  size_t OFF_FEAT  = 0;                          // n*128 ushorts = n*64 floats
  size_t OFF_EL    = OFF_FEAT + (size_t)n * 64;
  size_t OFF_ER    = OFF_EL + (size_t)n * 8;
  size_t OFF_ROFD  = OFF_ER + (size_t)n * 8;
  size_t OFF_ROFS  = OFF_ROFD + (size_t)(n + 16);
  size_t OFF_EIDD  = OFF_ROFS + (size_t)(n + 16);
  size_t OFF_SRCD  = OFF_EIDD + (size_t)e;
  size_t OFF_EIDS  = OFF_SRCD + (size_t)e;
  size_t OFF_APERM = OFF_EIDS + (size_t)e;       // bf16: e*8 ushorts = e*4 floats
  size_t OFF_PART  = OFF_APERM + (size_t)e * 4;
  size_t OFF_META  = OFF_PART + (size_t)gridMsg * 256;
  size_t OFF_BN    = OFF_META + 1200;

  ushort_t* featbf = (ushort_t*)(ws + OFF_FEAT);
  float*    el     = ws + OFF_EL;
  float*    er     = ws + OFF_ER;
  unsigned* roffD  = (unsigned*)(ws + OFF_ROFD);
  unsigned* roffS  = (unsigned*)(ws + OFF_ROFS);
  unsigned* eidD   = (unsigned*)(ws + OFF_EIDD);
  int*      srcD   = (int*)(ws + OFF_SRCD);
  unsigned* eidS   = (unsigned*)(ws + OFF_EIDS);
  ushort_t* apermB = (ushort_t*)(ws + OFF_APERM);
  float*    partial= ws + OFF_PART;
  unsigned* meta   = (unsigned*)(ws + OFF_META);
  float*    bnsum  = ws + OFF_BN;   // bnacc[256] = bnsum[128] ++ bnsq[128]
  float*    mu     = bnsum + 256;
  float*    scale  = bnsum + 384;
  float*    tr     = el;  // alias: el dead after k_finB (dst half)
  float*    swD    = er;  // alias: er dead after k_finB (dst half)

  float* hout = (float*)d_out;
  float* attn = (float*)d_out + (size_t)n * 128;
  uint2*    recD = (uint2*)attn;                          // dead once k_attn writes attn
  unsigned* recS = (unsigned*)(attn + (size_t)e * 2);

  hipMemsetAsync(meta, 0, 800 * sizeof(unsigned), stream);   // hists+flags+curb
  hipMemsetAsync(bnsum, 0, 256 * sizeof(float), stream);
  size_t head = (size_t)n * 128 + (size_t)e * 8;
  if ((size_t)out_size > head)
    hipMemsetAsync((float*)d_out + head, 0, ((size_t)out_size - head) * sizeof(float), stream);

  k_gemm<<<CDIV(n, 64), 256, 0, stream>>>(h_in, fc_w, attn_l, attn_r, featbf, el, er, n);

  // bucket sort (both graphs): single fused hist+scan+scatter launch
  k_sort<<<nblkE, 256, 0, stream>>>(esrc, edst, meta, roffD, roffS, recD, recS,
                                    nbkt, n, e, nblkE);
  // fine placement, dst+src combined
  k_finB<<<2 * nbkt, 256, 0, stream>>>(recD, recS, meta, el, er, roffD, roffS,
                                       apermB, srcD, eidD, eidS, nbkt, n);

  // fused softmax + dst-half R (pure LDS serial loops) + writebacks
  k_attn<<<CDIV(n, 32), 256, 0, stream>>>(roffD, eidD, apermB, aw1, ab1, aw2, ab2,
                                          attn, swD, n);
  // src-half via attn-row gather (linearized MLP) + t_relu
  k_sumw_tr<<<CDIV(n, 32), 256, 0, stream>>>(roffS, eidS, attn, swD, aw1, ab1, aw2, ab2,
                                             tw1, tb1, tr, n);

  // message aggregation + e_emb + BN partials
  k_msg<<<gridMsg, 256, 0, stream>>>(srcD, roffD, apermB, featbf, tr, tw2, tb2, gat_bias,
                                     hout, partial, n);
  // BN reduce + last-block finalize (r5-proven), then full-grid epilogue
  k_red<<<nblkR, 256, 0, stream>>>(partial, bnsum, gamma, mu, scale, meta + 399,
                                   gridMsg, n, nblkR);
  k_final<<<CDIV(n * 32, 256), 256, 0, stream>>>(h_in, hout, mu, scale, beta, n * 32);
}

// Round 10
// 320.154 us; speedup vs baseline: 1.1320x; 1.0110x over previous
//
#include <hip/hip_runtime.h>
#include <math.h>

#define CDIV(a,b) (((a)+(b)-1)/(b))
#define SEGCAP 768  // max edges per 32-node group in LDS fast path (mean 384)

typedef unsigned short ushort_t;

__device__ __forceinline__ ushort_t f2bf(float x) {
  unsigned u = __float_as_uint(x);
  unsigned r = (u + 0x7FFFu + ((u >> 16) & 1u)) >> 16;
  return (ushort_t)r;
}
__device__ __forceinline__ float bf2f(ushort_t s) {
  return __uint_as_float(((unsigned)s) << 16);
}

typedef __attribute__((ext_vector_type(8))) short bf16x8;
typedef __attribute__((ext_vector_type(4))) float f32x4;

// ---------------------------------------------------------------------------
// K1 (MFMA): feat = h @ fc_w.T via split-bf16 (hi+lo). el/er via an EXTRA
// 16-col MFMA tile: B_e[k][j] = wl[k][j] (j<8) / wr[k][j-8], where
// wl = fc_w.T·al blockdiag (computed per block in fp32, split to bf16 LDS).
// Wave wv computes the el/er tile for its own 16-row tile -- replaces the
// 256-shfl/lane butterfly epilogue.
// ---------------------------------------------------------------------------
__global__ __launch_bounds__(256) void k_gemm(const float* __restrict__ hm,
                                              const float* __restrict__ w,
                                              const float* __restrict__ al,
                                              const float* __restrict__ ar,
                                              ushort_t* __restrict__ featbf,
                                              float* __restrict__ el,
                                              float* __restrict__ er, int n) {
  __shared__ ushort_t Ahi[64 * 128];          // 16KB, XOR-swizzled rows
  __shared__ ushort_t Alo[64 * 128];          // 16KB
  __shared__ ushort_t BeL[4][4][16][16];      // 8KB: [kt][lg][lr][8 hi | 8 lo]
  const int t = threadIdx.x;
  const int wv = t >> 6;   // wave 0..3
  const int l = t & 63;    // lane
  const int lr = l & 15;   // row-in-tile (A) / col-in-tile (B,C)
  const int lg = l >> 4;   // k-group 0..3

  // ---- phase 0: wlr[k][j] fp32 in LDS (reuse Ahi region as float buffer) ----
  float* wlr = (float*)Ahi;  // [128][16]
  {
    int k = t >> 1, j0 = (t & 1) * 8;
    const float* av = (t & 1) ? ar : al;
    float out[8];
#pragma unroll
    for (int jh = 0; jh < 8; ++jh) out[jh] = 0.f;
#pragma unroll
    for (int jh = 0; jh < 8; ++jh) {
#pragma unroll
      for (int d = 0; d < 16; ++d) {
        out[jh] += w[(size_t)(jh * 16 + d) * 128 + k] * av[jh * 16 + d];
      }
    }
#pragma unroll
    for (int jh = 0; jh < 8; ++jh) wlr[k * 16 + j0 + jh] = out[jh];
  }
  __syncthreads();
  // ---- phase 1: one wave extracts+splits B_e into BeL ----
  if (t < 64) {
#pragma unroll
    for (int kt = 0; kt < 4; ++kt) {
      float xs[8];
#pragma unroll
      for (int i = 0; i < 8; ++i) xs[i] = wlr[(kt * 32 + lg * 8 + i) * 16 + lr];
#pragma unroll
      for (int i = 0; i < 8; ++i) {
        unsigned u = __float_as_uint(xs[i]);
        BeL[kt][lg][lr][i] = (ushort_t)(u >> 16);
        float resid = xs[i] - __uint_as_float(u & 0xFFFF0000u);
        BeL[kt][lg][lr][8 + i] = (ushort_t)(__float_as_uint(resid) >> 16);
      }
    }
  }

  // ---- B fragments (feat cols): fc_w split to bf16 hi/lo in registers ----
  bf16x8 Bhi[4][2], Blo[4][2];
#pragma unroll
  for (int ct = 0; ct < 2; ++ct) {
    const float* wr = w + (size_t)(32 * wv + ct * 16 + lr) * 128;
#pragma unroll
    for (int kt = 0; kt < 4; ++kt) {
      const float* wp = wr + kt * 32 + lg * 8;
      float4 v0 = *(const float4*)wp;
      float4 v1 = *(const float4*)(wp + 4);
      float xs[8] = {v0.x, v0.y, v0.z, v0.w, v1.x, v1.y, v1.z, v1.w};
      bf16x8 hi, lo;
#pragma unroll
      for (int i = 0; i < 8; ++i) {
        unsigned u = __float_as_uint(xs[i]);
        hi[i] = (short)(u >> 16);
        float resid = xs[i] - __uint_as_float(u & 0xFFFF0000u);
        lo[i] = (short)(__float_as_uint(resid) >> 16);
      }
      Bhi[kt][ct] = hi;
      Blo[kt][ct] = lo;
    }
  }
  __syncthreads();  // BeL ready; wlr region free for A staging

  const int base = blockIdx.x * 64;
#pragma unroll
  for (int r8 = 0; r8 < 8; ++r8) {
    int f = t + 256 * r8;
    int row = f >> 5, c4 = f & 31;
    int nidx = base + row;
    float4 v = make_float4(0.f, 0.f, 0.f, 0.f);
    if (nidx < n) v = ((const float4*)hm)[(size_t)nidx * 32 + c4];
    unsigned ux = __float_as_uint(v.x), uy = __float_as_uint(v.y);
    unsigned uz = __float_as_uint(v.z), uw = __float_as_uint(v.w);
    unsigned hi0 = (ux >> 16) | (uy & 0xFFFF0000u);
    unsigned hi1 = (uz >> 16) | (uw & 0xFFFF0000u);
    float rx = v.x - __uint_as_float(ux & 0xFFFF0000u);
    float ry = v.y - __uint_as_float(uy & 0xFFFF0000u);
    float rz = v.z - __uint_as_float(uz & 0xFFFF0000u);
    float rw = v.w - __uint_as_float(uw & 0xFFFF0000u);
    unsigned lo0 = (__float_as_uint(rx) >> 16) | (__float_as_uint(ry) & 0xFFFF0000u);
    unsigned lo1 = (__float_as_uint(rz) >> 16) | (__float_as_uint(rw) & 0xFFFF0000u);
    int uidx = row * 128 + ((c4 * 4) ^ ((row & 7) << 3));
    *(uint2*)&Ahi[uidx] = make_uint2(hi0, hi1);
    *(uint2*)&Alo[uidx] = make_uint2(lo0, lo1);
  }
  __syncthreads();

  f32x4 acc[4][2];
  f32x4 acce = (f32x4){0.f, 0.f, 0.f, 0.f};
#pragma unroll
  for (int mt = 0; mt < 4; ++mt)
#pragma unroll
    for (int ct = 0; ct < 2; ++ct) acc[mt][ct] = (f32x4){0.f, 0.f, 0.f, 0.f};

#pragma unroll
  for (int mt = 0; mt < 4; ++mt) {
    const int row = mt * 16 + lr;
    const int rbase = row * 128;
    const int swz = (row & 7) << 3;
#pragma unroll
    for (int kt = 0; kt < 4; ++kt) {
      const int k0 = (kt * 32 + lg * 8) ^ swz;
      bf16x8 ah = *(const bf16x8*)&Ahi[rbase + k0];
      bf16x8 ao = *(const bf16x8*)&Alo[rbase + k0];
#pragma unroll
      for (int ct = 0; ct < 2; ++ct) {
        acc[mt][ct] = __builtin_amdgcn_mfma_f32_16x16x32_bf16(ah, Bhi[kt][ct], acc[mt][ct], 0, 0, 0);
        acc[mt][ct] = __builtin_amdgcn_mfma_f32_16x16x32_bf16(ah, Blo[kt][ct], acc[mt][ct], 0, 0, 0);
        acc[mt][ct] = __builtin_amdgcn_mfma_f32_16x16x32_bf16(ao, Bhi[kt][ct], acc[mt][ct], 0, 0, 0);
      }
      if (mt == wv) {  // wave-uniform: this wave's el/er row-tile
        bf16x8 behi = *(const bf16x8*)&BeL[kt][lg][lr][0];
        bf16x8 belo = *(const bf16x8*)&BeL[kt][lg][lr][8];
        acce = __builtin_amdgcn_mfma_f32_16x16x32_bf16(ah, behi, acce, 0, 0, 0);
        acce = __builtin_amdgcn_mfma_f32_16x16x32_bf16(ah, belo, acce, 0, 0, 0);
        acce = __builtin_amdgcn_mfma_f32_16x16x32_bf16(ao, behi, acce, 0, 0, 0);
      }
    }
  }

  // ---- el/er epilogue: C layout col=lr (j), row=lg*4+rg ----
#pragma unroll
  for (int rg = 0; rg < 4; ++rg) {
    int node = base + wv * 16 + lg * 4 + rg;
    if (node < n) {
      if (lr < 8) el[(size_t)node * 8 + lr] = acce[rg];
      else        er[(size_t)node * 8 + (lr - 8)] = acce[rg];
    }
  }

  // ---- featbf: scatter acc -> LDS [row][col] bf16, then full-line stores ----
  __syncthreads();
#pragma unroll
  for (int mt = 0; mt < 4; ++mt)
#pragma unroll
    for (int ct = 0; ct < 2; ++ct) {
      const int colw = 32 * wv + ct * 16 + lr;
#pragma unroll
      for (int rg = 0; rg < 4; ++rg) {
        int row = mt * 16 + lg * 4 + rg;
        Ahi[row * 128 + colw] = f2bf(acc[mt][ct][rg]);
      }
    }
  __syncthreads();
#pragma unroll
  for (int r4 = 0; r4 < 4; ++r4) {
    int f = t + 256 * r4;
    int row = f >> 4, q = f & 15;
    int node = base + row;
    if (node < n)
      ((uint4*)featbf)[(size_t)node * 16 + q] = *(const uint4*)&Ahi[row * 128 + q * 8];
  }
}

// ---------------------------------------------------------------------------
// K-hist: coarse histograms for BOTH graphs (bucket = key>>8) + last-block
// fused exclusive scans -> bktoffD(meta+800)/curbD(meta+400),
// bktoffS(meta+1000)/curbS(meta+600). NO spin: scan results are consumed by
// the NEXT kernels (kernel boundary = cheap grid barrier; r9's in-kernel
// spin barrier cost ~45us of fences + flag polling).
// meta: histD@0..195 histS@200..395 histticket@398 redticket@399
//       curbD@400.. curbS@600.. bktoffD@800.. bktoffS@1000..
// ---------------------------------------------------------------------------
__global__ __launch_bounds__(256) void k_hist(const int* __restrict__ src,
                                              const int* __restrict__ dst,
                                              unsigned* __restrict__ meta,
                                              unsigned* __restrict__ roffD,
                                              unsigned* __restrict__ roffS,
                                              int nbkt, int n, int e, int nblk) {
  __shared__ unsigned lhD[256], lhS[256];
  __shared__ unsigned s[256];
  __shared__ unsigned isLast;
  int t = threadIdx.x;
  lhD[t] = 0; lhS[t] = 0;
  __syncthreads();
  int base = blockIdx.x * 4096;
  for (int k = 0; k < 16; ++k) {
    int i = base + t + 256 * k;
    if (i < e) {
      atomicAdd(&lhD[((unsigned)dst[i]) >> 8], 1u);
      atomicAdd(&lhS[((unsigned)src[i]) >> 8], 1u);
    }
  }
  __syncthreads();
  if (t < nbkt) {
    if (lhD[t]) atomicAdd(&meta[t], lhD[t]);
    if (lhS[t]) atomicAdd(&meta[200 + t], lhS[t]);
  }
  __threadfence();
  if (t == 0) isLast = (atomicAdd(&meta[398], 1u) == (unsigned)(nblk - 1)) ? 1u : 0u;
  __syncthreads();
  if (!isLast) return;
  for (int g = 0; g < 2; ++g) {
    unsigned v = (t < nbkt) ? atomicAdd(&meta[g * 200 + t], 0u) : 0u;  // coherent read
    s[t] = v;
    __syncthreads();
    for (int off = 1; off < 256; off <<= 1) {
      unsigned x = (t >= off) ? s[t - off] : 0u;
      __syncthreads();
      s[t] += x;
      __syncthreads();
    }
    unsigned excl = s[t] - v;
    if (t < nbkt) {
      meta[800 + g * 200 + t] = excl;
      meta[400 + g * 200 + t] = excl;
    }
    if (t == 0) meta[800 + g * 200 + nbkt] = (unsigned)e;
    __syncthreads();
  }
  if (t == 0) { roffD[n] = (unsigned)e; roffS[n] = (unsigned)e; }
}

// Pass A: count, reserve, re-read & place (dense contiguous runs per bucket).
__global__ __launch_bounds__(256) void k_scatterA(const int* __restrict__ src,
                                                  const int* __restrict__ dst,
                                                  unsigned* __restrict__ curbD,
                                                  unsigned* __restrict__ curbS,
                                                  uint2* __restrict__ recD,
                                                  unsigned* __restrict__ recS,
                                                  int nbkt, int e) {
  __shared__ unsigned lhD[256], lhS[256], lcD[256], lcS[256];
  int t = threadIdx.x;
  lhD[t] = 0; lhS[t] = 0;
  __syncthreads();
  int base = blockIdx.x * 4096;
  for (int k = 0; k < 16; ++k) {
    int i = base + t + 256 * k;
    if (i < e) {
      atomicAdd(&lhD[((unsigned)dst[i]) >> 8], 1u);
      atomicAdd(&lhS[((unsigned)src[i]) >> 8], 1u);
    }
  }
  __syncthreads();
  if (t < nbkt) {
    lcD[t] = lhD[t] ? atomicAdd(&curbD[t], lhD[t]) : 0u;
    lcS[t] = lhS[t] ? atomicAdd(&curbS[t], lhS[t]) : 0u;
  }
  __syncthreads();
  for (int k = 0; k < 16; ++k) {
    int i = base + t + 256 * k;
    if (i < e) {
      unsigned d2 = (unsigned)dst[i], s2 = (unsigned)src[i];
      unsigned pD = atomicAdd(&lcD[d2 >> 8], 1u);
      recD[pD] = make_uint2(((d2 & 255u) << 16) | s2, (unsigned)i);
      unsigned pS = atomicAdd(&lcS[s2 >> 8], 1u);
      recS[pS] = ((s2 & 255u) << 24) | (unsigned)i;
    }
  }
}

// ---------------------------------------------------------------------------
// K-finB (combined dst+src fine placement, grid = 2*nbkt): b<nbkt -> dst path
// (+ fused edge-e leaky_relu -> bf16 aperm); else src path (eidS payload).
// Pure per-block work -- no cross-block sync.
// ---------------------------------------------------------------------------
__global__ __launch_bounds__(256) void k_finB(const uint2* __restrict__ recD,
                                              const unsigned* __restrict__ recS,
                                              const unsigned* __restrict__ meta,
                                              const float* __restrict__ el,
                                              const float* __restrict__ er,
                                              unsigned* __restrict__ roffD,
                                              unsigned* __restrict__ roffS,
                                              ushort_t* __restrict__ apermB,
                                              int* __restrict__ srcD,
                                              unsigned* __restrict__ eidD,
                                              unsigned* __restrict__ eidS,
                                              int nbkt, int n) {
  __shared__ float erL[256 * 8];
  __shared__ unsigned cnt1[256], cnt2[256], sc[256];
  int t = threadIdx.x;
  int b = blockIdx.x;
  if (b < nbkt) {
    const unsigned* bktoff = meta + 800;
    unsigned b0 = bktoff[b], b1 = bktoff[b + 1];
    int nb0 = b << 8;
    for (int k = 0; k < 8; ++k) {
      int idx = t + 256 * k;
      int node = nb0 + (idx >> 3);
      erL[idx] = (node < n) ? er[(size_t)nb0 * 8 + idx] : 0.f;
    }
    cnt1[t] = 0;
    __syncthreads();
    for (unsigned j = b0 + t; j < b1; j += 256) {
      unsigned nodeLoc = (recD[j].x >> 16) & 255u;
      atomicAdd(&cnt1[nodeLoc], 1u);
    }
    __syncthreads();
    unsigned v = cnt1[t];
    sc[t] = v;
    __syncthreads();
    for (int off = 1; off < 256; off <<= 1) {
      unsigned x = (t >= off) ? sc[t - off] : 0u;
      __syncthreads();
      sc[t] += x;
      __syncthreads();
    }
    unsigned excl = sc[t] - v;
    int node = nb0 + t;
    if (node < n) roffD[node] = b0 + excl;
    cnt2[t] = b0 + excl;
    __syncthreads();
    for (unsigned j = b0 + t; j < b1; j += 256) {
      uint2 r = recD[j];
      unsigned nodeLoc = (r.x >> 16) & 255u;
      unsigned srcv = r.x & 0xFFFFu;
      unsigned pos = atomicAdd(&cnt2[nodeLoc], 1u);
      float4 a0 = *(const float4*)&el[(size_t)srcv * 8];
      float4 a1 = *(const float4*)&el[(size_t)srcv * 8 + 4];
      const float* eb = &erL[nodeLoc * 8];
      float ev[8] = {a0.x + eb[0], a0.y + eb[1], a0.z + eb[2], a0.w + eb[3],
                     a1.x + eb[4], a1.y + eb[5], a1.z + eb[6], a1.w + eb[7]};
#pragma unroll
      for (int h2 = 0; h2 < 8; ++h2) ev[h2] = ev[h2] > 0.f ? ev[h2] : 0.2f * ev[h2];
      unsigned q0 = (unsigned)f2bf(ev[0]) | ((unsigned)f2bf(ev[1]) << 16);
      unsigned q1 = (unsigned)f2bf(ev[2]) | ((unsigned)f2bf(ev[3]) << 16);
      unsigned q2 = (unsigned)f2bf(ev[4]) | ((unsigned)f2bf(ev[5]) << 16);
      unsigned q3 = (unsigned)f2bf(ev[6]) | ((unsigned)f2bf(ev[7]) << 16);
      *(uint4*)&apermB[(size_t)pos * 8] = make_uint4(q0, q1, q2, q3);
      srcD[pos] = (int)srcv;
      eidD[pos] = r.y;
    }
  } else {
    int bs = b - nbkt;
    const unsigned* bktoff = meta + 1000;
    unsigned b0 = bktoff[bs], b1 = bktoff[bs + 1];
    int nb0 = bs << 8;
    cnt1[t] = 0;
    __syncthreads();
    for (unsigned j = b0 + t; j < b1; j += 256) {
      unsigned nodeLoc = recS[j] >> 24;
      atomicAdd(&cnt1[nodeLoc], 1u);
    }
    __syncthreads();
    unsigned v = cnt1[t];
    sc[t] = v;
    __syncthreads();
    for (int off = 1; off < 256; off <<= 1) {
      unsigned x = (t >= off) ? sc[t - off] : 0u;
      __syncthreads();
      sc[t] += x;
      __syncthreads();
    }
    unsigned excl = sc[t] - v;
    int node = nb0 + t;
    if (node < n) roffS[node] = b0 + excl;
    cnt2[t] = b0 + excl;
    __syncthreads();
    for (unsigned j = b0 + t; j < b1; j += 256) {
      unsigned r = recS[j];
      unsigned nodeLoc = r >> 24;
      unsigned pos = atomicAdd(&cnt2[nodeLoc], 1u);
      eidS[pos] = r & 0x00FFFFFFu;
    }
  }
}

// ---------------------------------------------------------------------------
// K-attn (fused): softmax -> dst-half R-accumulation (linearity: sum_w =
// deg*(1-B2) - W2·R) -> per-edge writeback. Serial per-(node,h) loops are
// pure LDS+VALU; normalize pass folded into MLP pass via inv-prescaled W1.
// ---------------------------------------------------------------------------
__global__ __launch_bounds__(256) void k_attn(const unsigned* __restrict__ roffD,
                                              const unsigned* __restrict__ eidD,
                                              ushort_t* __restrict__ apermB,
                                              const float* __restrict__ aw1,
                                              const float* __restrict__ ab1,
                                              const float* __restrict__ aw2,
                                              const float* __restrict__ ab2,
                                              float* __restrict__ attn,
                                              float* __restrict__ swD, int n) {
  __shared__ float aL[SEGCAP * 8];
  __shared__ float W1[64], W2[64], B1[8], B2[8];
  __shared__ unsigned nb_[33];
  int t = threadIdx.x;
  if (t < 64) { W1[t] = aw1[t]; W2[t] = aw2[t]; }
  else if (t < 72) { B1[t - 64] = ab1[t - 64]; B2[t - 64] = ab2[t - 64]; }
  int g0 = blockIdx.x * 32;
  if (t < 33) {
    int node = g0 + t;
    nb_[t] = roffD[node < n ? node : n];
  }
  __syncthreads();
  unsigned b0 = nb_[0], b1 = nb_[32];
  unsigned count = b1 - b0;
  int ln = t >> 3, h = t & 7;
  int node = g0 + ln;
  const int l = t & 63, gbl = l & 56;
  if (count <= SEGCAP) {
    const unsigned* ap32 = (const unsigned*)apermB + (size_t)b0 * 4;
    for (unsigned k = t; k < count * 4; k += 256) {
      unsigned pk = ap32[k];
      aL[k * 2] = bf2f((ushort_t)(pk & 0xFFFFu));
      aL[k * 2 + 1] = bf2f((ushort_t)(pk >> 16));
    }
    __syncthreads();
    unsigned s0 = nb_[ln] - b0, s1 = nb_[ln + 1] - b0;
    float inv = 0.f;
    if (node < n) {
      float ssum = 0.f;
      for (unsigned j = s0; j < s1; ++j) {
        float ex = expf(aL[j * 8 + h]);
        aL[j * 8 + h] = ex;
        ssum += ex;
      }
      inv = ssum > 0.f ? 1.f / ssum : 0.f;
    }
    __syncthreads();
    float w1m[8];
#pragma unroll
    for (int m = 0; m < 8; ++m) w1m[m] = W1[h * 8 + m] * __shfl(inv, gbl | m);
    if (node < n) {
      float R = 0.f;
      for (unsigned j = s0; j < s1; ++j) {
        const float* a = &aL[j * 8];
        float acc = B1[h];
#pragma unroll
        for (int m = 0; m < 8; ++m) acc += a[m] * w1m[m];
        acc = acc > 0.f ? acc : 0.f;
        R += acc;
        aL[j * 8 + h] = a[h] * inv;  // normalize own slot (folded pass)
      }
      float sv = (float)(s1 - s0) * (1.f - B2[h]);
#pragma unroll
      for (int r = 0; r < 8; ++r) {
        int jj = (h + r) & 7;
        float Rj = __shfl(R, gbl | jj);
        sv -= W2[h * 8 + jj] * Rj;
      }
      swD[(size_t)node * 8 + h] = sv;
    }
    __syncthreads();
    for (unsigned eL = t; eL < count; eL += 256) {
      const float* a = &aL[eL * 8];
      unsigned ee = eidD[b0 + eL];
      float4* op = (float4*)&attn[(size_t)ee * 8];
      op[0] = make_float4(a[0], a[1], a[2], a[3]);
      op[1] = make_float4(a[4], a[5], a[6], a[7]);
      unsigned q0 = (unsigned)f2bf(a[0]) | ((unsigned)f2bf(a[1]) << 16);
      unsigned q1 = (unsigned)f2bf(a[2]) | ((unsigned)f2bf(a[3]) << 16);
      unsigned q2 = (unsigned)f2bf(a[4]) | ((unsigned)f2bf(a[5]) << 16);
      unsigned q3 = (unsigned)f2bf(a[6]) | ((unsigned)f2bf(a[7]) << 16);
      *(uint4*)&apermB[(size_t)(b0 + eL) * 8] = make_uint4(q0, q1, q2, q3);
    }
  } else {
    unsigned sb = nb_[ln], se = nb_[ln + 1];
    if (node < n) {
      float s = 0.f;
      for (unsigned j = sb; j < se; ++j) s += expf(bf2f(apermB[(size_t)j * 8 + h]));
      float inv = s > 0.f ? 1.f / s : 0.f;
      for (unsigned j = sb; j < se; ++j) {
        size_t p = (size_t)j * 8 + h;
        apermB[p] = f2bf(expf(bf2f(apermB[p])) * inv);
      }
    }
    __syncthreads();
    if (node < n) {
      float R = 0.f;
      for (unsigned j = sb; j < se; ++j) {
        float a[8];
#pragma unroll
        for (int m = 0; m < 8; ++m) a[m] = bf2f(apermB[(size_t)j * 8 + m]);
        float acc = B1[h];
#pragma unroll
        for (int m = 0; m < 8; ++m) acc += a[m] * W1[h * 8 + m];
        acc = acc > 0.f ? acc : 0.f;
        R += acc;
      }
      float sv = (float)(se - sb) * (1.f - B2[h]);
#pragma unroll
      for (int r = 0; r < 8; ++r) {
        int jj = (h + r) & 7;
        float Rj = __shfl(R, gbl | jj);
        sv -= W2[h * 8 + jj] * Rj;
      }
      swD[(size_t)node * 8 + h] = sv;
    }
    for (unsigned eL = t; eL < count; eL += 256) {
      unsigned j = b0 + eL;
      float a[8];
#pragma unroll
      for (int m = 0; m < 8; ++m) a[m] = bf2f(apermB[(size_t)j * 8 + m]);
      unsigned ee = eidD[j];
      float4* op = (float4*)&attn[(size_t)ee * 8];
      op[0] = make_float4(a[0], a[1], a[2], a[3]);
      op[1] = make_float4(a[4], a[5], a[6], a[7]);
    }
  }
}

// K5: src-half sum_w via fp32 attn-row gather (eidS coalesced; same-row lanes
// wave-merged; 4-wide unrolled gathers). Lane h computes only hidden unit h.
__global__ __launch_bounds__(256) void k_sumw_tr(const unsigned* __restrict__ roffS,
                                                 const unsigned* __restrict__ eidS,
                                                 const float* __restrict__ attn,
                                                 const float* __restrict__ swD,
                                                 const float* __restrict__ aw1,
                                                 const float* __restrict__ ab1,
                                                 const float* __restrict__ aw2,
                                                 const float* __restrict__ ab2,
                                                 const float* __restrict__ tw1,
                                                 const float* __restrict__ tb1,
                                                 float* __restrict__ tr, int n) {
  __shared__ float sw[32][9];
  __shared__ float W1[64], W2[64], T1[64], B1[8], B2[8], TB[8];
  int t = threadIdx.x;
  if (t < 64) { W1[t] = aw1[t]; W2[t] = aw2[t]; T1[t] = tw1[t]; }
  else if (t < 72) { B1[t - 64] = ab1[t - 64]; B2[t - 64] = ab2[t - 64]; TB[t - 64] = tb1[t - 64]; }
  __syncthreads();
  int ln = t >> 3, h = t & 7;
  int node = blockIdx.x * 32 + ln;
  const int gbl = (t & 63) & 56;
  float w1r[8];
#pragma unroll
  for (int m = 0; m < 8; ++m) w1r[m] = W1[h * 8 + m];
  const float B1h = B1[h];
  if (node < n) {
    unsigned b = roffS[node], en = roffS[node + 1];
    float R = 0.f;
    unsigned j = b;
    for (; j + 4 <= en; j += 4) {
      unsigned e0 = eidS[j], e1 = eidS[j + 1], e2 = eidS[j + 2], e3 = eidS[j + 3];
      const float* p0 = &attn[(size_t)e0 * 8];
      const float* p1 = &attn[(size_t)e1 * 8];
      const float* p2 = &attn[(size_t)e2 * 8];
      const float* p3 = &attn[(size_t)e3 * 8];
      float4 x00 = *(const float4*)p0, x01 = *(const float4*)(p0 + 4);
      float4 x10 = *(const float4*)p1, x11 = *(const float4*)(p1 + 4);
      float4 x20 = *(const float4*)p2, x21 = *(const float4*)(p2 + 4);
      float4 x30 = *(const float4*)p3, x31 = *(const float4*)(p3 + 4);
      float a0 = B1h + x00.x * w1r[0] + x00.y * w1r[1] + x00.z * w1r[2] + x00.w * w1r[3]
                     + x01.x * w1r[4] + x01.y * w1r[5] + x01.z * w1r[6] + x01.w * w1r[7];
      float a1 = B1h + x10.x * w1r[0] + x10.y * w1r[1] + x10.z * w1r[2] + x10.w * w1r[3]
                     + x11.x * w1r[4] + x11.y * w1r[5] + x11.z * w1r[6] + x11.w * w1r[7];
      float a2 = B1h + x20.x * w1r[0] + x20.y * w1r[1] + x20.z * w1r[2] + x20.w * w1r[3]
                     + x21.x * w1r[4] + x21.y * w1r[5] + x21.z * w1r[6] + x21.w * w1r[7];
      float a3 = B1h + x30.x * w1r[0] + x30.y * w1r[1] + x30.z * w1r[2] + x30.w * w1r[3]
                     + x31.x * w1r[4] + x31.y * w1r[5] + x31.z * w1r[6] + x31.w * w1r[7];
      R += (a0 > 0.f ? a0 : 0.f) + (a1 > 0.f ? a1 : 0.f) +
           (a2 > 0.f ? a2 : 0.f) + (a3 > 0.f ? a3 : 0.f);
    }
    for (; j < en; ++j) {
      unsigned e0 = eidS[j];
      const float* p0 = &attn[(size_t)e0 * 8];
      float4 x00 = *(const float4*)p0, x01 = *(const float4*)(p0 + 4);
      float a0 = B1h + x00.x * w1r[0] + x00.y * w1r[1] + x00.z * w1r[2] + x00.w * w1r[3]
                     + x01.x * w1r[4] + x01.y * w1r[5] + x01.z * w1r[6] + x01.w * w1r[7];
      R += a0 > 0.f ? a0 : 0.f;
    }
    float sv = swD[(size_t)node * 8 + h] + (float)(en - b) * (1.f - B2[h]);
#pragma unroll
    for (int r = 0; r < 8; ++r) {
      int jj = (h + r) & 7;
      float Rj = __shfl(R, gbl | jj);
      sv -= W2[h * 8 + jj] * Rj;
    }
    sw[ln][h] = sv;
  }
  __syncthreads();
  if (node < n) {
    float acc = TB[h];
#pragma unroll
    for (int m = 0; m < 8; ++m) acc += sw[ln][m] * T1[h * 8 + m];
    tr[(size_t)node * 8 + h] = acc > 0.f ? acc : 0.f;
  }
}

// K-msg (fused e_emb + BN stats): r1 form (measured 43.2us @ occ 54% --
// deeper pipelines r2/r3 both regressed; gather stream is occupancy/TLP-fed).
__global__ __launch_bounds__(256) void k_msg(const int* __restrict__ srcD,
                                             const unsigned* __restrict__ roff,
                                             const ushort_t* __restrict__ apermB,
                                             const ushort_t* __restrict__ featbf,
                                             const float* __restrict__ tr,
                                             const float* __restrict__ tw2,
                                             const float* __restrict__ tb2,
                                             const float* __restrict__ gat_bias,
                                             float* __restrict__ hout,
                                             float* __restrict__ partial, int n) {
  __shared__ float bn1[4][128], bn2[4][128];
  int t = threadIdx.x;
  int w = t >> 6, lane = t & 63;
  int col = lane * 2;
  int hh = lane >> 3;
  float w2a[8], w2b[8];
#pragma unroll
  for (int j = 0; j < 8; ++j) { w2a[j] = tw2[col * 8 + j]; w2b[j] = tw2[(col + 1) * 8 + j]; }
  float biasA = tb2[col] + gat_bias[col];
  float biasB = tb2[col + 1] + gat_bias[col + 1];
  float s1a = 0.f, s1b = 0.f, s2a = 0.f, s2b = 0.f;
  int nodeBase = blockIdx.x * 16 + w * 4;
  for (int ni = 0; ni < 4; ++ni) {
    int node = nodeBase + ni;
    if (node >= n) break;
    unsigned b = roff[node], en = roff[node + 1];
    float x0 = 0.f, x1 = 0.f;
    unsigned j = b;
    for (; j + 4 <= en; j += 4) {
      int sa = srcD[j], sb = srcD[j + 1], sc2 = srcD[j + 2], sd = srcD[j + 3];
      float av0 = bf2f(apermB[(size_t)j * 8 + hh]);
      float av1 = bf2f(apermB[(size_t)(j + 1) * 8 + hh]);
      float av2 = bf2f(apermB[(size_t)(j + 2) * 8 + hh]);
      float av3 = bf2f(apermB[(size_t)(j + 3) * 8 + hh]);
      unsigned p0 = *(const unsigned*)&featbf[(size_t)sa * 128 + col];
      unsigned p1 = *(const unsigned*)&featbf[(size_t)sb * 128 + col];
      unsigned p2 = *(const unsigned*)&featbf[(size_t)sc2 * 128 + col];
      unsigned p3 = *(const unsigned*)&featbf[(size_t)sd * 128 + col];
      x0 += bf2f((ushort_t)(p0 & 0xFFFFu)) * av0 + bf2f((ushort_t)(p1 & 0xFFFFu)) * av1 +
            bf2f((ushort_t)(p2 & 0xFFFFu)) * av2 + bf2f((ushort_t)(p3 & 0xFFFFu)) * av3;
      x1 += bf2f((ushort_t)(p0 >> 16)) * av0 + bf2f((ushort_t)(p1 >> 16)) * av1 +
            bf2f((ushort_t)(p2 >> 16)) * av2 + bf2f((ushort_t)(p3 >> 16)) * av3;
    }
    for (; j < en; ++j) {
      int sa = srcD[j];
      float av0 = bf2f(apermB[(size_t)j * 8 + hh]);
      unsigned p0 = *(const unsigned*)&featbf[(size_t)sa * 128 + col];
      x0 += bf2f((ushort_t)(p0 & 0xFFFFu)) * av0;
      x1 += bf2f((ushort_t)(p0 >> 16)) * av0;
    }
    const float* trn = &tr[(size_t)node * 8];
    float emA = biasA, emB = biasB;
#pragma unroll
    for (int jj = 0; jj < 8; ++jj) {
      float tv = trn[jj];
      emA += tv * w2a[jj];
      emB += tv * w2b[jj];
    }
    float v0 = x0 + emA, v1 = x1 + emB;
    *(float2*)&hout[(size_t)node * 128 + col] = make_float2(v0, v1);
    s1a += v0; s1b += v1; s2a += v0 * v0; s2b += v1 * v1;
  }
  bn1[w][col] = s1a; bn1[w][col + 1] = s1b;
  bn2[w][col] = s2a; bn2[w][col + 1] = s2b;
  __syncthreads();
  int f = t & 127;
  float acc;
  if (t < 128) acc = bn1[0][f] + bn1[1][f] + bn1[2][f] + bn1[3][f];
  else         acc = bn2[0][f] + bn2[1][f] + bn2[2][f] + bn2[3][f];
  partial[(size_t)blockIdx.x * 256 + t] = acc;
}

// Reduce per-block BN partials + fused last-block finalize (mu/scale).
// (r5-proven form; mu/scale consumed by the NEXT kernel -> plain stores OK.)
__global__ __launch_bounds__(256) void k_red(const float* __restrict__ partial,
                                             float* __restrict__ bnacc,
                                             const float* __restrict__ gamma,
                                             float* __restrict__ mu,
                                             float* __restrict__ scale,
                                             unsigned* __restrict__ ticket,
                                             int rows, int n, int nblk) {
  __shared__ unsigned isLast;
  int t = threadIdx.x;
  int r0 = blockIdx.x * 13, r1 = r0 + 13;
  if (r1 > rows) r1 = rows;
  float acc = 0.f;
  for (int r = r0; r < r1; ++r) acc += partial[(size_t)r * 256 + t];
  if (r0 < r1) atomicAdd(&bnacc[t], acc);
  __threadfence();
  if (t == 0) isLast = (atomicAdd(ticket, 1u) == (unsigned)(nblk - 1)) ? 1u : 0u;
  __syncthreads();
  if (isLast && t < 128) {
    float sm = atomicAdd(&bnacc[t], 0.f);         // coherent reads
    float sq = atomicAdd(&bnacc[128 + t], 0.f);
    float m = sm / (float)n;
    float v = sq / (float)n - m * m;
    mu[t] = m;
    scale[t] = rsqrtf(v + 1e-5f) * gamma[t];
  }
}

// K7: out = h_in + elu((x - mu)*scale + beta)  -- full grid, BW-bound.
__global__ void k_final(const float* __restrict__ hin, float* __restrict__ hout,
                        const float* __restrict__ mu, const float* __restrict__ scale,
                        const float* __restrict__ beta, int total4) {
  int i = blockIdx.x * blockDim.x + threadIdx.x;
  if (i >= total4) return;
  int c = (i & 31) * 4;
  float4 x = ((const float4*)hout)[i];
  float4 m4 = *(const float4*)&mu[c];
  float4 s4 = *(const float4*)&scale[c];
  float4 b4 = *(const float4*)&beta[c];
  float4 hi = ((const float4*)hin)[i];
  float y0 = (x.x - m4.x) * s4.x + b4.x;
  float y1 = (x.y - m4.y) * s4.y + b4.y;
  float y2 = (x.z - m4.z) * s4.z + b4.z;
  float y3 = (x.w - m4.w) * s4.w + b4.w;
  y0 = y0 > 0.f ? y0 : expm1f(y0);
  y1 = y1 > 0.f ? y1 : expm1f(y1);
  y2 = y2 > 0.f ? y2 : expm1f(y2);
  y3 = y3 > 0.f ? y3 : expm1f(y3);
  float4 o = make_float4(hi.x + y0, hi.y + y1, hi.z + y2, hi.w + y3);
  ((float4*)hout)[i] = o;
}

extern "C" void kernel_launch(void* const* d_in, const int* in_sizes, int n_in,
                              void* d_out, int out_size, void* d_ws, size_t ws_size,
                              hipStream_t stream) {
  const float* h_in     = (const float*)d_in[0];
  const int*   esrc     = (const int*)d_in[1];
  const int*   edst     = (const int*)d_in[2];
  const float* fc_w     = (const float*)d_in[4];
  const float* attn_l   = (const float*)d_in[5];
  const float* attn_r   = (const float*)d_in[6];
  const float* gat_bias = (const float*)d_in[7];
  const float* aw1      = (const float*)d_in[8];
  const float* ab1      = (const float*)d_in[9];
  const float* aw2      = (const float*)d_in[10];
  const float* ab2      = (const float*)d_in[11];
  const float* tw1      = (const float*)d_in[12];
  const float* tb1      = (const float*)d_in[13];
  const float* tw2      = (const float*)d_in[14];
  const float* tb2      = (const float*)d_in[15];
  const float* gamma    = (const float*)d_in[16];
  const float* beta     = (const float*)d_in[17];

  const int n = in_sizes[0] / 128;  // 50000
  const int e = in_sizes[1];        // 600000
  const int nbkt = CDIV(n, 256);    // 196
  const int gridMsg = CDIV(n, 16);  // 3125
  const int nblkE = CDIV(e, 4096);  // 147
  const int nblkR = CDIV(gridMsg, 13);  // 241

  float* ws = (float*)d_ws;
  size_t OFF_FEAT  = 0;                          // n*128 ushorts = n*64 floats
  size_t OFF_EL    = OFF_FEAT + (size_t)n * 64;
  size_t OFF_ER    = OFF_EL + (size_t)n * 8;
  size_t OFF_ROFD  = OFF_ER + (size_t)n * 8;
  size_t OFF_ROFS  = OFF_ROFD + (size_t)(n + 16);
  size_t OFF_EIDD  = OFF_ROFS + (size_t)(n + 16);
  size_t OFF_SRCD  = OFF_EIDD + (size_t)e;
  size_t OFF_EIDS  = OFF_SRCD + (size_t)e;
  size_t OFF_APERM = OFF_EIDS + (size_t)e;       // bf16: e*8 ushorts = e*4 floats
  size_t OFF_PART  = OFF_APERM + (size_t)e * 4;
  size_t OFF_META  = OFF_PART + (size_t)gridMsg * 256;
  size_t OFF_BN    = OFF_META + 1200;

  ushort_t* featbf = (ushort_t*)(ws + OFF_FEAT);
  float*    el     = ws + OFF_EL;
  float*    er     = ws + OFF_ER;
  unsigned* roffD  = (unsigned*)(ws + OFF_ROFD);
  unsigned* roffS  = (unsigned*)(ws + OFF_ROFS);
  unsigned* eidD   = (unsigned*)(ws + OFF_EIDD);
  int*      srcD   = (int*)(ws + OFF_SRCD);
  unsigned* eidS   = (unsigned*)(ws + OFF_EIDS);
  ushort_t* apermB = (ushort_t*)(ws + OFF_APERM);
  float*    partial= ws + OFF_PART;
  unsigned* meta   = (unsigned*)(ws + OFF_META);
  float*    bnsum  = ws + OFF_BN;   // bnacc[256] = bnsum[128] ++ bnsq[128]
  float*    mu     = bnsum + 256;
  float*    scale  = bnsum + 384;
  float*    tr     = el;  // alias: el dead after k_finB (dst half)
  float*    swD    = er;  // alias: er dead after k_finB (dst half)

  float* hout = (float*)d_out;
  float* attn = (float*)d_out + (size_t)n * 128;
  uint2*    recD = (uint2*)attn;                          // dead once k_attn writes attn
  unsigned* recS = (unsigned*)(attn + (size_t)e * 2);

  hipMemsetAsync(meta, 0, 800 * sizeof(unsigned), stream);   // hists+tickets+curb
  hipMemsetAsync(bnsum, 0, 256 * sizeof(float), stream);
  size_t head = (size_t)n * 128 + (size_t)e * 8;
  if ((size_t)out_size > head)
    hipMemsetAsync((float*)d_out + head, 0, ((size_t)out_size - head) * sizeof(float), stream);

  k_gemm<<<CDIV(n, 64), 256, 0, stream>>>(h_in, fc_w, attn_l, attn_r, featbf, el, er, n);

  // bucket sort (both graphs): hist+scan, then count/reserve/place
  k_hist<<<nblkE, 256, 0, stream>>>(esrc, edst, meta, roffD, roffS, nbkt, n, e, nblkE);
  k_scatterA<<<nblkE, 256, 0, stream>>>(esrc, edst, meta + 400, meta + 600,
                                        recD, recS, nbkt, e);
  // fine placement, dst+src combined
  k_finB<<<2 * nbkt, 256, 0, stream>>>(recD, recS, meta, el, er, roffD, roffS,
                                       apermB, srcD, eidD, eidS, nbkt, n);

  // fused softmax + dst-half R (pure LDS serial loops) + writebacks
  k_attn<<<CDIV(n, 32), 256, 0, stream>>>(roffD, eidD, apermB, aw1, ab1, aw2, ab2,
                                          attn, swD, n);
  // src-half via attn-row gather (linearized MLP) + t_relu
  k_sumw_tr<<<CDIV(n, 32), 256, 0, stream>>>(roffS, eidS, attn, swD, aw1, ab1, aw2, ab2,
                                             tw1, tb1, tr, n);

  // message aggregation + e_emb + BN partials
  k_msg<<<gridMsg, 256, 0, stream>>>(srcD, roffD, apermB, featbf, tr, tw2, tb2, gat_bias,
                                     hout, partial, n);
  // BN reduce + last-block finalize (r5-proven), then full-grid epilogue
  k_red<<<nblkR, 256, 0, stream>>>(partial, bnsum, gamma, mu, scale, meta + 399,
                                   gridMsg, n, nblkR);
  k_final<<<CDIV(n * 32, 256), 256, 0, stream>>>(h_in, hout, mu, scale, beta, n * 32);
}